// Round 9
// baseline (573.967 us; speedup 1.0000x reference)
//
#include <hip/hip_runtime.h>
#include <math.h>

#define BB   2
#define SS   1024
#define HH   768
#define DD   24
#define HIDD 96
#define VINN 2304   // 3*H
#define VHIDD 768
#define NRR  2048   // BB*SS

typedef __attribute__((ext_vector_type(8))) short short8;
typedef __attribute__((ext_vector_type(4))) float floatx4;

static __device__ inline unsigned short f2bf(float x) {
    unsigned int u = __float_as_uint(x);
    u = (u + 0x7FFFu + ((u >> 16) & 1u)) >> 16;
    return (unsigned short)u;
}
static __device__ inline unsigned int pack2(float a, float b) {
    return (unsigned int)f2bf(a) | ((unsigned int)f2bf(b) << 16);
}

// async global -> LDS, 16 B per lane; LDS dest = wave-uniform base + lane*16
static __device__ inline void gl16(const unsigned short* g, unsigned short* l) {
    __builtin_amdgcn_global_load_lds(
        (const __attribute__((address_space(1))) unsigned int*)g,
        (__attribute__((address_space(3))) unsigned int*)l,
        16, 0, 0);
}

// ---------------- Kernel 0: f32 -> bf16 transpose-convert ------------------
__global__ __launch_bounds__(256) void k_tconv(
    const float* __restrict__ in, unsigned short* __restrict__ out,
    int R, int C)
{
    size_t zoff = (size_t)blockIdx.z * R * C;
    in += zoff; out += zoff;
    __shared__ float tile[32][33];
    int r0 = blockIdx.y * 32, c0 = blockIdx.x * 32;
    int tc = threadIdx.x & 31, tr = threadIdx.x >> 5;
    #pragma unroll
    for (int i = 0; i < 4; ++i)
        tile[tr + i*8][tc] = in[(size_t)(r0 + tr + i*8)*C + c0 + tc];
    __syncthreads();
    #pragma unroll
    for (int i = 0; i < 4; ++i)
        out[(size_t)(c0 + tr + i*8)*R + r0 + tc] = f2bf(tile[tc][tr + i*8]);
}

// ---------------- Kernel 1: Z projections via MFMA, packed-bf16 output -----
__global__ __launch_bounds__(256) void k_zproj(
    const float* __restrict__ Hj, const float* __restrict__ Hi,
    const float* __restrict__ Wpj, const float* __restrict__ Wpi,
    unsigned* __restrict__ Zjp, unsigned* __restrict__ Zip)
{
    __shared__ __align__(16) unsigned short sA[64][72];
    __shared__ __align__(16) unsigned short sBT[32][72];
    int tid = threadIdx.x;
    int w = tid >> 6, lane = tid & 63;
    int quad = lane >> 4, col = lane & 15;

    int m0 = blockIdx.x * 64;
    bool isJ = (m0 < NRR);
    const float* src = isJ ? Hj : Hi;
    const float* Wp  = isJ ? Wpj : Wpi;
    unsigned* Zp     = isJ ? Zjp : Zip;
    int rowbase = isJ ? m0 : (m0 - NRR);

    floatx4 acc[2];
    acc[0] = (floatx4){0.f,0.f,0.f,0.f};
    acc[1] = (floatx4){0.f,0.f,0.f,0.f};

    for (int kb = 0; kb < HH; kb += 64) {
        #pragma unroll
        for (int i = 0; i < 4; ++i) {
            int f4 = tid + i*256;
            int r = f4 >> 4, c4 = f4 & 15;
            float4 v = *(const float4*)(src + (size_t)(rowbase + r)*HH + kb + c4*4);
            uint2 pkt; pkt.x = pack2(v.x, v.y); pkt.y = pack2(v.z, v.w);
            *(uint2*)&sA[r][c4*4] = pkt;
        }
        {
            const float* wsrc = Wp + (size_t)kb*DD;
            #pragma unroll
            for (int i = 0; i < 6; ++i) {
                int idx = tid + i*256;
                int k = idx / DD, n = idx % DD;
                sBT[n][k] = f2bf(wsrc[idx]);
            }
        }
        __syncthreads();
        #pragma unroll
        for (int kt = 0; kt < 2; ++kt) {
            short8 av = *(const short8*)&sA[w*16 + col][kt*32 + quad*8];
            #pragma unroll
            for (int nt = 0; nt < 2; ++nt) {
                short8 bv = *(const short8*)&sBT[nt*16 + col][kt*32 + quad*8];
                acc[nt] = __builtin_amdgcn_mfma_f32_16x16x32_bf16(av, bv, acc[nt], 0, 0, 0);
            }
        }
        __syncthreads();
    }
    #pragma unroll
    for (int nt = 0; nt < 2; ++nt) {
        #pragma unroll
        for (int r = 0; r < 4; ++r) {
            float v = acc[nt][r];
            float vn = __shfl_xor(v, 1, 64);
            int n = nt*16 + col;
            if (!(col & 1) && n < DD) {
                int m = w*16 + quad*4 + r;
                Zp[(size_t)(rowbase + m)*12 + (n >> 1)] = pack2(v, vn);
            }
        }
    }
}

// ---------------- Kernel 2: MFMA logits + softmax -> probs (bf16) ----------
#define LSTR 72
#define TC 128
__global__ __launch_bounds__(256) void k_attn(
    const unsigned* __restrict__ Zjp, const unsigned* __restrict__ Zip,
    const float* __restrict__ W1, const float* __restrict__ b1,
    const float* __restrict__ W2,
    const float* __restrict__ mask, unsigned short* __restrict__ probs)
{
    int row = blockIdx.x;       // b*S + s
    int b = row >> 10;
    int tid = threadIdx.x;
    int lane = tid & 63, wv = tid >> 6;
    int quad = lane >> 4, col = lane & 15;

    __shared__ __align__(16) unsigned short sAB[2][TC*LSTR]; // B-build in [0], then A dbuf
    __shared__ __align__(16) float sLog[SS];
    __shared__ unsigned sZjp[12];
    __shared__ float sW2[HIDD];
    __shared__ float sRed[4];

    if (tid < 12) sZjp[tid] = Zjp[(size_t)row*12 + tid];
    if (tid < HIDD) sW2[tid] = W2[tid];
    __syncthreads();

    if (tid < HIDD) {
        int h = tid;
        float zj[24];
        #pragma unroll
        for (int u = 0; u < 12; ++u) {
            unsigned z = sZjp[u];
            zj[2*u]   = __uint_as_float(z << 16);
            zj[2*u+1] = __uint_as_float(z & 0xffff0000u);
        }
        float tj = b1[h];
        #pragma unroll
        for (int d = 0; d < DD; ++d) tj = fmaf(zj[d], W1[d*HIDD + h], tj);
        unsigned short* rowp = &sAB[0][h*LSTR];
        #pragma unroll
        for (int d = 0; d < DD; ++d)
            rowp[d] = f2bf(fmaf(zj[d], W1[(48+d)*HIDD + h], W1[(24+d)*HIDD + h]));
        #pragma unroll
        for (int d = 0; d < DD; ++d)
            rowp[24+d] = f2bf(W1[(72+d)*HIDD + h]);
        rowp[48] = f2bf(tj);
        #pragma unroll
        for (int k = 49; k < 64; ++k) rowp[k] = 0;
    }
    __syncthreads();

    short8 bfr[6][2];
    #pragma unroll
    for (int nf = 0; nf < 6; ++nf)
        #pragma unroll
        for (int kt = 0; kt < 2; ++kt)
            bfr[nf][kt] = *(const short8*)&sAB[0][(nf*16 + col)*LSTR + kt*32 + quad*8];
    float4 w2q[6];
    #pragma unroll
    for (int nf = 0; nf < 6; ++nf)
        w2q[nf] = *(const float4*)&sW2[nf*16 + quad*4];
    __syncthreads();   // sAB now reused as A double-buffer

    {
        int r = tid >> 1, bf = tid & 1;
        unsigned short* rowp = &sAB[bf][r*LSTR];
        uint4 w0; w0.x = 0x3F80u; w0.y = 0; w0.z = 0; w0.w = 0;
        *(uint4*)&rowp[48] = w0;
        uint4 zz; zz.x = 0; zz.y = 0; zz.z = 0; zz.w = 0;
        *(uint4*)&rowp[56] = zz;
    }

    int t_loc = tid >> 1, hh = tid & 1;
    const unsigned* zbase = Zip + (size_t)(b << 10) * 12;

    auto pack = [&](int chunk, int bf) {
        int t = chunk*TC + t_loc;
        const unsigned* zr = zbase + (size_t)t*12;
        unsigned short* rowp = &sAB[bf][t_loc*LSTR];
        uint4 first = *(const uint4*)(zr + hh*4);
        *(uint4*)&rowp[hh*8] = first;
        uint2 ext; ext.x = 0; ext.y = 0;
        if (hh) {
            uint4 second = *(const uint4*)(zr + 8);
            *(uint4*)&rowp[16] = second;
            unsigned myz[6] = {first.z, first.w, second.x, second.y, second.z, second.w};
            unsigned q[6];
            #pragma unroll
            for (int u = 0; u < 6; ++u) {
                unsigned za = sZjp[6 + u], zb = myz[u];
                float alo = __uint_as_float(za << 16);
                float ahi = __uint_as_float(za & 0xffff0000u);
                float blo = __uint_as_float(zb << 16);
                float bhi = __uint_as_float(zb & 0xffff0000u);
                unsigned dlo = __float_as_uint(fabsf(alo - blo)) + 0x8000u;
                unsigned dhi = __float_as_uint(fabsf(ahi - bhi)) + 0x8000u;
                q[u] = __builtin_amdgcn_perm(dhi, dlo, 0x07060302u);
            }
            #pragma unroll
            for (int j = 0; j < 3; ++j) {
                uint2 wq; wq.x = q[2*j]; wq.y = q[2*j+1];
                *(uint2*)&rowp[36 + 4*j] = wq;
            }
        } else {
            ext = *(const uint2*)(zr + 4);
            unsigned myz[6] = {first.x, first.y, first.z, first.w, ext.x, ext.y};
            unsigned q[6];
            #pragma unroll
            for (int u = 0; u < 6; ++u) {
                unsigned za = sZjp[u], zb = myz[u];
                float alo = __uint_as_float(za << 16);
                float ahi = __uint_as_float(za & 0xffff0000u);
                float blo = __uint_as_float(zb << 16);
                float bhi = __uint_as_float(zb & 0xffff0000u);
                unsigned dlo = __float_as_uint(fabsf(alo - blo)) + 0x8000u;
                unsigned dhi = __float_as_uint(fabsf(ahi - bhi)) + 0x8000u;
                q[u] = __builtin_amdgcn_perm(dhi, dlo, 0x07060302u);
            }
            #pragma unroll
            for (int j = 0; j < 3; ++j) {
                uint2 wq; wq.x = q[2*j]; wq.y = q[2*j+1];
                *(uint2*)&rowp[24 + 4*j] = wq;
            }
        }
    };

    pack(0, 0);
    __syncthreads();

    for (int chunk = 0; chunk < SS/TC; ++chunk) {
        int cur = chunk & 1;
        if (chunk + 1 < SS/TC) pack(chunk + 1, cur ^ 1);

        short8 av[2][2];
        #pragma unroll
        for (int tt = 0; tt < 2; ++tt) {
            int arow = (wv*2 + tt)*16 + col;
            av[tt][0] = *(const short8*)&sAB[cur][arow*LSTR + quad*8];
            av[tt][1] = *(const short8*)&sAB[cur][arow*LSTR + 32 + quad*8];
        }
        float s0 = 0.f, s1 = 0.f;
        #pragma unroll
        for (int hf = 0; hf < 6; ++hf) {
            floatx4 a0 = {0.f,0.f,0.f,0.f}, a1 = {0.f,0.f,0.f,0.f};
            a0 = __builtin_amdgcn_mfma_f32_16x16x32_bf16(bfr[hf][0], av[0][0], a0, 0, 0, 0);
            a0 = __builtin_amdgcn_mfma_f32_16x16x32_bf16(bfr[hf][1], av[0][1], a0, 0, 0, 0);
            a1 = __builtin_amdgcn_mfma_f32_16x16x32_bf16(bfr[hf][0], av[1][0], a1, 0, 0, 0);
            a1 = __builtin_amdgcn_mfma_f32_16x16x32_bf16(bfr[hf][1], av[1][1], a1, 0, 0, 0);
            float w2v[4] = {w2q[hf].x, w2q[hf].y, w2q[hf].z, w2q[hf].w};
            #pragma unroll
            for (int r = 0; r < 4; ++r) {
                s0 = fmaf(fmaxf(a0[r], 0.f), w2v[r], s0);
                s1 = fmaf(fmaxf(a1[r], 0.f), w2v[r], s1);
            }
        }
        s0 += __shfl_xor(s0, 16, 64);  s0 += __shfl_xor(s0, 32, 64);
        s1 += __shfl_xor(s1, 16, 64);  s1 += __shfl_xor(s1, 32, 64);
        if (lane < 16) {
            sLog[chunk*TC + (wv*2 + 0)*16 + lane] = s0;
            sLog[chunk*TC + (wv*2 + 1)*16 + lane] = s1;
        }
        __syncthreads();
    }

    // ---- softmax ----
    float lv[4];
    #pragma unroll
    for (int i = 0; i < 4; ++i) {
        int t = tid + i*256;
        lv[i] = sLog[t] + (1.0f - mask[(size_t)(b<<10) + t]) * (-3.402823466e+38f);
    }
    float m = fmaxf(fmaxf(lv[0], lv[1]), fmaxf(lv[2], lv[3]));
    #pragma unroll
    for (int off = 32; off; off >>= 1) m = fmaxf(m, __shfl_down(m, off, 64));
    if (lane == 0) sRed[wv] = m;
    __syncthreads();
    float M = fmaxf(fmaxf(sRed[0], sRed[1]), fmaxf(sRed[2], sRed[3]));
    float e[4]; float ssum = 0.f;
    #pragma unroll
    for (int i = 0; i < 4; ++i) { e[i] = expf(lv[i] - M); ssum += e[i]; }
    #pragma unroll
    for (int off = 32; off; off >>= 1) ssum += __shfl_down(ssum, off, 64);
    __syncthreads();
    if (lane == 0) sRed[wv] = ssum;
    __syncthreads();
    float inv = 1.0f / (sRed[0] + sRed[1] + sRed[2] + sRed[3]);
    #pragma unroll
    for (int i = 0; i < 4; ++i)
        probs[(size_t)row*SS + tid + i*256] = f2bf(e[i] * inv);
}

// ---------------- Kernel 3: split-K GEMM with atomic fused epilogue --------
// 128M x 64N tile, BK=64, gl16 staging, split-K=4. Each block writes its f32
// partial (tile-contiguous, 32 KB), bumps a per-tile counter; last block
// re-reads all 4 partials (L2-hot) and applies the epilogue.
// MODE 0: msgin builder   MODE 1: bf16(relu(+bias))   MODE 2: f32(alpha*(+bias))
template<int MODE>
__global__ __launch_bounds__(256) void k_mgemm_f(
    const unsigned short* __restrict__ A,
    const unsigned short* __restrict__ BT,
    float* __restrict__ P, int* __restrict__ ctr,
    const float* __restrict__ bias,
    const float* __restrict__ Hj,
    const float* __restrict__ alpha_p,
    void* __restrict__ Cout,
    int K, int bt_bstride)
{
    __shared__ __align__(16) unsigned short sA[128*64];
    __shared__ __align__(16) unsigned short sB[64*64];
    __shared__ int sTicket;
    int tid = threadIdx.x;
    int w = tid >> 6, lane = tid & 63;
    int quad = lane >> 4, col = lane & 15;

    int n0 = blockIdx.x * 64, m0 = blockIdx.y * 128;
    int tile = blockIdx.y * gridDim.x + blockIdx.x;      // 0..191
    int z = blockIdx.z;
    int kslice = K >> 2;
    int k0 = z * kslice;
    int nk = kslice >> 6;
    const unsigned short* Bb = BT + (size_t)(m0 >> 10) * bt_bstride;

    int srow = lane >> 3;
    int skc  = (lane & 7) * 8;

    floatx4 acc[2][4];
    #pragma unroll
    for (int mt = 0; mt < 2; ++mt)
        #pragma unroll
        for (int nf = 0; nf < 4; ++nf)
            acc[mt][nf] = (floatx4){0.f,0.f,0.f,0.f};

    for (int kb = 0; kb < nk; ++kb) {
        int kofs = k0 + kb*64;
        #pragma unroll
        for (int i = 0; i < 4; ++i) {
            int rbase = w*32 + i*8;
            gl16(A + (size_t)(m0 + rbase + srow)*K + kofs + skc, &sA[rbase*64]);
        }
        #pragma unroll
        for (int i = 0; i < 2; ++i) {
            int rbase = w*16 + i*8;
            gl16(Bb + (size_t)(n0 + rbase + srow)*K + kofs + skc, &sB[rbase*64]);
        }
        __syncthreads();
        #pragma unroll
        for (int kt = 0; kt < 2; ++kt) {
            short8 av[2];
            #pragma unroll
            for (int mt = 0; mt < 2; ++mt)
                av[mt] = *(const short8*)&sA[(w*32 + mt*16 + col)*64 + kt*32 + quad*8];
            #pragma unroll
            for (int nf = 0; nf < 4; ++nf) {
                short8 bv = *(const short8*)&sB[(nf*16 + col)*64 + kt*32 + quad*8];
                #pragma unroll
                for (int mt = 0; mt < 2; ++mt)
                    acc[mt][nf] = __builtin_amdgcn_mfma_f32_16x16x32_bf16(
                        av[mt], bv, acc[mt][nf], 0, 0, 0);
            }
        }
        __syncthreads();
    }

    // ---- write own partial (tile-contiguous slot) ----
    float* Pz = P + ((size_t)tile*4 + z)*(128*64);
    #pragma unroll
    for (int mt = 0; mt < 2; ++mt) {
        #pragma unroll
        for (int nf = 0; nf < 4; ++nf) {
            int n = nf*16 + col;
            #pragma unroll
            for (int r = 0; r < 4; ++r) {
                int m = w*32 + mt*16 + quad*4 + r;
                Pz[m*64 + n] = acc[mt][nf][r];
            }
        }
    }

    // ---- release + ticket ----
    __threadfence();
    __syncthreads();
    if (tid == 0) sTicket = atomicAdd(&ctr[tile], 1);
    __syncthreads();
    if (sTicket != 3) return;

    // ---- last block: acquire, reduce 4 partials, epilogue ----
    __threadfence();
    const float* Pt = P + (size_t)tile*4*(128*64);
    float alpha = (MODE == 2) ? alpha_p[0] : 1.0f;
    #pragma unroll
    for (int i = 0; i < 8; ++i) {
        int e = i*256 + tid;                 // float4 index: 2048 total
        int m = e >> 4, c4 = (e & 15)*4;     // m 0..127, col 0..63 by 4
        float4 v = *(const float4*)(Pt + m*64 + c4);
        #pragma unroll
        for (int zz = 1; zz < 4; ++zz) {
            float4 vz = *(const float4*)(Pt + zz*(128*64) + m*64 + c4);
            v.x += vz.x; v.y += vz.y; v.z += vz.z; v.w += vz.w;
        }
        size_t g = (size_t)(m0 + m);
        int n = n0 + c4;
        if (MODE == 0) {
            float4 h4 = *(const float4*)(Hj + g*HH + n);
            unsigned short* msgin = (unsigned short*)Cout;
            uint2 wc, wh, wp;
            wc.x = pack2(v.x, v.y);          wc.y = pack2(v.z, v.w);
            wh.x = pack2(h4.x, h4.y);        wh.y = pack2(h4.z, h4.w);
            wp.x = pack2(v.x*h4.x, v.y*h4.y);
            wp.y = pack2(v.z*h4.z, v.w*h4.w);
            *(uint2*)&msgin[g*VINN + n]        = wc;
            *(uint2*)&msgin[g*VINN + HH + n]   = wh;
            *(uint2*)&msgin[g*VINN + 2*HH + n] = wp;
        } else if (MODE == 1) {
            float4 b4 = *(const float4*)(bias + n);
            uint2 wy;
            wy.x = pack2(fmaxf(v.x+b4.x, 0.f), fmaxf(v.y+b4.y, 0.f));
            wy.y = pack2(fmaxf(v.z+b4.z, 0.f), fmaxf(v.w+b4.w, 0.f));
            *(uint2*)&((unsigned short*)Cout)[g*VHIDD + n] = wy;
        } else {
            float4 b4 = *(const float4*)(bias + n);
            float4 o;
            o.x = alpha*(v.x+b4.x); o.y = alpha*(v.y+b4.y);
            o.z = alpha*(v.z+b4.z); o.w = alpha*(v.w+b4.w);
            *(float4*)&((float*)Cout)[g*HH + n] = o;
        }
    }
}

extern "C" void kernel_launch(void* const* d_in, const int* in_sizes, int n_in,
                              void* d_out, int out_size, void* d_ws, size_t ws_size,
                              hipStream_t stream)
{
    const float* Hj   = (const float*)d_in[0];
    const float* Hi   = (const float*)d_in[1];
    const float* mask = (const float*)d_in[2];
    const float* Wpj  = (const float*)d_in[3];
    const float* Wpi  = (const float*)d_in[4];
    const float* W1   = (const float*)d_in[5];
    const float* b1   = (const float*)d_in[6];
    const float* W2   = (const float*)d_in[7];
    const float* Wv1  = (const float*)d_in[9];
    const float* bv1  = (const float*)d_in[10];
    const float* Wv2  = (const float*)d_in[11];
    const float* bv2  = (const float*)d_in[12];
    const float* alpha = (const float*)d_in[13];
    float* out = (float*)d_out;

    const int NR = NRR;                   // 2048
    char* p = (char*)d_ws;
    auto alloc = [&](size_t bytes) {
        char* r = p; p += (bytes + 255) & ~(size_t)255; return r;
    };
    unsigned* Zjp          = (unsigned*)alloc((size_t)NR*12*4);
    unsigned* Zip          = (unsigned*)alloc((size_t)NR*12*4);
    unsigned short* probsb = (unsigned short*)alloc((size_t)NR*SS*2);
    unsigned short* HiT    = (unsigned short*)alloc((size_t)BB*HH*SS*2);
    unsigned short* Wv1T   = (unsigned short*)alloc((size_t)VHIDD*VINN*2);
    unsigned short* Wv2T   = (unsigned short*)alloc((size_t)HH*VHIDD*2);
    unsigned short* msginb = (unsigned short*)alloc((size_t)NR*VINN*2);
    unsigned short* Y1b    = (unsigned short*)alloc((size_t)NR*VHIDD*2);
    float* Part            = (float*)alloc((size_t)192*4*128*64*4);
    int*   Ctr             = (int*)alloc((size_t)3*192*4);

    hipMemsetAsync(Ctr, 0, (size_t)3*192*4, stream);

    k_tconv<<<dim3(VHIDD/32, VINN/32, 1), 256, 0, stream>>>(Wv1, Wv1T, VINN, VHIDD);
    k_tconv<<<dim3(HH/32, VHIDD/32, 1), 256, 0, stream>>>(Wv2, Wv2T, VHIDD, HH);
    k_tconv<<<dim3(HH/32, SS/32, BB), 256, 0, stream>>>(Hi, HiT, SS, HH);
    k_zproj<<<2*NR/64, 256, 0, stream>>>(Hj, Hi, Wpj, Wpi, Zjp, Zip);
    k_attn<<<NR, 256, 0, stream>>>(Zjp, Zip, W1, b1, W2, mask, probsb);

    // ctx GEMM: M=2048 (batch via bt stride), N=768, K=1024, split 4
    k_mgemm_f<0><<<dim3(HH/64, NR/128, 4), 256, 0, stream>>>(
        probsb, HiT, Part, Ctr + 0*192, nullptr, Hj, alpha, msginb, SS, HH*SS);

    // MLP GEMM1: K=2304, split 4
    k_mgemm_f<1><<<dim3(VHIDD/64, NR/128, 4), 256, 0, stream>>>(
        msginb, Wv1T, Part, Ctr + 1*192, bv1, nullptr, alpha, Y1b, VINN, 0);

    // MLP GEMM2: K=768, split 4
    k_mgemm_f<2><<<dim3(HH/64, NR/128, 4), 256, 0, stream>>>(
        Y1b, Wv2T, Part, Ctr + 2*192, bv2, nullptr, alpha, out, VHIDD, 0);
}

// Round 10
// 216.912 us; speedup vs baseline: 2.6461x; 2.6461x over previous
//
#include <hip/hip_runtime.h>
#include <math.h>

#define BB   2
#define SS   1024
#define HH   768
#define DD   24
#define HIDD 96
#define VINN 2304   // 3*H
#define VHIDD 768
#define NRR  2048   // BB*SS

typedef __attribute__((ext_vector_type(8))) short short8;
typedef __attribute__((ext_vector_type(4))) float floatx4;

static __device__ inline unsigned short f2bf(float x) {
    unsigned int u = __float_as_uint(x);
    u = (u + 0x7FFFu + ((u >> 16) & 1u)) >> 16;
    return (unsigned short)u;
}
static __device__ inline unsigned int pack2(float a, float b) {
    return (unsigned int)f2bf(a) | ((unsigned int)f2bf(b) << 16);
}

// async global -> LDS, 16 B per lane; LDS dest = wave-uniform base + lane*16
static __device__ inline void gl16(const unsigned short* g, unsigned short* l) {
    __builtin_amdgcn_global_load_lds(
        (const __attribute__((address_space(1))) unsigned int*)g,
        (__attribute__((address_space(3))) unsigned int*)l,
        16, 0, 0);
}

// ---------------- Kernel 0: f32 -> bf16 transpose-convert ------------------
__global__ __launch_bounds__(256) void k_tconv(
    const float* __restrict__ in, unsigned short* __restrict__ out,
    int R, int C)
{
    size_t zoff = (size_t)blockIdx.z * R * C;
    in += zoff; out += zoff;
    __shared__ float tile[32][33];
    int r0 = blockIdx.y * 32, c0 = blockIdx.x * 32;
    int tc = threadIdx.x & 31, tr = threadIdx.x >> 5;
    #pragma unroll
    for (int i = 0; i < 4; ++i)
        tile[tr + i*8][tc] = in[(size_t)(r0 + tr + i*8)*C + c0 + tc];
    __syncthreads();
    #pragma unroll
    for (int i = 0; i < 4; ++i)
        out[(size_t)(c0 + tr + i*8)*R + r0 + tc] = f2bf(tile[tc][tr + i*8]);
}

// ---------------- Kernel 1: Z projections via MFMA, packed-bf16 output -----
__global__ __launch_bounds__(256) void k_zproj(
    const float* __restrict__ Hj, const float* __restrict__ Hi,
    const float* __restrict__ Wpj, const float* __restrict__ Wpi,
    unsigned* __restrict__ Zjp, unsigned* __restrict__ Zip)
{
    __shared__ __align__(16) unsigned short sA[64][72];
    __shared__ __align__(16) unsigned short sBT[32][72];
    int tid = threadIdx.x;
    int w = tid >> 6, lane = tid & 63;
    int quad = lane >> 4, col = lane & 15;

    int m0 = blockIdx.x * 64;
    bool isJ = (m0 < NRR);
    const float* src = isJ ? Hj : Hi;
    const float* Wp  = isJ ? Wpj : Wpi;
    unsigned* Zp     = isJ ? Zjp : Zip;
    int rowbase = isJ ? m0 : (m0 - NRR);

    floatx4 acc[2];
    acc[0] = (floatx4){0.f,0.f,0.f,0.f};
    acc[1] = (floatx4){0.f,0.f,0.f,0.f};

    for (int kb = 0; kb < HH; kb += 64) {
        #pragma unroll
        for (int i = 0; i < 4; ++i) {
            int f4 = tid + i*256;
            int r = f4 >> 4, c4 = f4 & 15;
            float4 v = *(const float4*)(src + (size_t)(rowbase + r)*HH + kb + c4*4);
            uint2 pkt; pkt.x = pack2(v.x, v.y); pkt.y = pack2(v.z, v.w);
            *(uint2*)&sA[r][c4*4] = pkt;
        }
        {
            const float* wsrc = Wp + (size_t)kb*DD;
            #pragma unroll
            for (int i = 0; i < 6; ++i) {
                int idx = tid + i*256;
                int k = idx / DD, n = idx % DD;
                sBT[n][k] = f2bf(wsrc[idx]);
            }
        }
        __syncthreads();
        #pragma unroll
        for (int kt = 0; kt < 2; ++kt) {
            short8 av = *(const short8*)&sA[w*16 + col][kt*32 + quad*8];
            #pragma unroll
            for (int nt = 0; nt < 2; ++nt) {
                short8 bv = *(const short8*)&sBT[nt*16 + col][kt*32 + quad*8];
                acc[nt] = __builtin_amdgcn_mfma_f32_16x16x32_bf16(av, bv, acc[nt], 0, 0, 0);
            }
        }
        __syncthreads();
    }
    #pragma unroll
    for (int nt = 0; nt < 2; ++nt) {
        #pragma unroll
        for (int r = 0; r < 4; ++r) {
            float v = acc[nt][r];
            float vn = __shfl_xor(v, 1, 64);
            int n = nt*16 + col;
            if (!(col & 1) && n < DD) {
                int m = w*16 + quad*4 + r;
                Zp[(size_t)(rowbase + m)*12 + (n >> 1)] = pack2(v, vn);
            }
        }
    }
}

// ---------------- Kernel 2: MFMA logits + softmax -> probs (bf16) ----------
#define LSTR 72
#define TC 128
__global__ __launch_bounds__(256) void k_attn(
    const unsigned* __restrict__ Zjp, const unsigned* __restrict__ Zip,
    const float* __restrict__ W1, const float* __restrict__ b1,
    const float* __restrict__ W2,
    const float* __restrict__ mask, unsigned short* __restrict__ probs)
{
    int row = blockIdx.x;       // b*S + s
    int b = row >> 10;
    int tid = threadIdx.x;
    int lane = tid & 63, wv = tid >> 6;
    int quad = lane >> 4, col = lane & 15;

    __shared__ __align__(16) unsigned short sAB[2][TC*LSTR]; // B-build in [0], then A dbuf
    __shared__ __align__(16) float sLog[SS];
    __shared__ unsigned sZjp[12];
    __shared__ float sW2[HIDD];
    __shared__ float sRed[4];

    if (tid < 12) sZjp[tid] = Zjp[(size_t)row*12 + tid];
    if (tid < HIDD) sW2[tid] = W2[tid];
    __syncthreads();

    if (tid < HIDD) {
        int h = tid;
        float zj[24];
        #pragma unroll
        for (int u = 0; u < 12; ++u) {
            unsigned z = sZjp[u];
            zj[2*u]   = __uint_as_float(z << 16);
            zj[2*u+1] = __uint_as_float(z & 0xffff0000u);
        }
        float tj = b1[h];
        #pragma unroll
        for (int d = 0; d < DD; ++d) tj = fmaf(zj[d], W1[d*HIDD + h], tj);
        unsigned short* rowp = &sAB[0][h*LSTR];
        #pragma unroll
        for (int d = 0; d < DD; ++d)
            rowp[d] = f2bf(fmaf(zj[d], W1[(48+d)*HIDD + h], W1[(24+d)*HIDD + h]));
        #pragma unroll
        for (int d = 0; d < DD; ++d)
            rowp[24+d] = f2bf(W1[(72+d)*HIDD + h]);
        rowp[48] = f2bf(tj);
        #pragma unroll
        for (int k = 49; k < 64; ++k) rowp[k] = 0;
    }
    __syncthreads();

    short8 bfr[6][2];
    #pragma unroll
    for (int nf = 0; nf < 6; ++nf)
        #pragma unroll
        for (int kt = 0; kt < 2; ++kt)
            bfr[nf][kt] = *(const short8*)&sAB[0][(nf*16 + col)*LSTR + kt*32 + quad*8];
    float4 w2q[6];
    #pragma unroll
    for (int nf = 0; nf < 6; ++nf)
        w2q[nf] = *(const float4*)&sW2[nf*16 + quad*4];
    __syncthreads();   // sAB now reused as A double-buffer

    {
        int r = tid >> 1, bf = tid & 1;
        unsigned short* rowp = &sAB[bf][r*LSTR];
        uint4 w0; w0.x = 0x3F80u; w0.y = 0; w0.z = 0; w0.w = 0;
        *(uint4*)&rowp[48] = w0;
        uint4 zz; zz.x = 0; zz.y = 0; zz.z = 0; zz.w = 0;
        *(uint4*)&rowp[56] = zz;
    }

    int t_loc = tid >> 1, hh = tid & 1;
    const unsigned* zbase = Zip + (size_t)(b << 10) * 12;

    auto pack = [&](int chunk, int bf) {
        int t = chunk*TC + t_loc;
        const unsigned* zr = zbase + (size_t)t*12;
        unsigned short* rowp = &sAB[bf][t_loc*LSTR];
        uint4 first = *(const uint4*)(zr + hh*4);
        *(uint4*)&rowp[hh*8] = first;
        uint2 ext; ext.x = 0; ext.y = 0;
        if (hh) {
            uint4 second = *(const uint4*)(zr + 8);
            *(uint4*)&rowp[16] = second;
            unsigned myz[6] = {first.z, first.w, second.x, second.y, second.z, second.w};
            unsigned q[6];
            #pragma unroll
            for (int u = 0; u < 6; ++u) {
                unsigned za = sZjp[6 + u], zb = myz[u];
                float alo = __uint_as_float(za << 16);
                float ahi = __uint_as_float(za & 0xffff0000u);
                float blo = __uint_as_float(zb << 16);
                float bhi = __uint_as_float(zb & 0xffff0000u);
                unsigned dlo = __float_as_uint(fabsf(alo - blo)) + 0x8000u;
                unsigned dhi = __float_as_uint(fabsf(ahi - bhi)) + 0x8000u;
                q[u] = __builtin_amdgcn_perm(dhi, dlo, 0x07060302u);
            }
            #pragma unroll
            for (int j = 0; j < 3; ++j) {
                uint2 wq; wq.x = q[2*j]; wq.y = q[2*j+1];
                *(uint2*)&rowp[36 + 4*j] = wq;
            }
        } else {
            ext = *(const uint2*)(zr + 4);
            unsigned myz[6] = {first.x, first.y, first.z, first.w, ext.x, ext.y};
            unsigned q[6];
            #pragma unroll
            for (int u = 0; u < 6; ++u) {
                unsigned za = sZjp[u], zb = myz[u];
                float alo = __uint_as_float(za << 16);
                float ahi = __uint_as_float(za & 0xffff0000u);
                float blo = __uint_as_float(zb << 16);
                float bhi = __uint_as_float(zb & 0xffff0000u);
                unsigned dlo = __float_as_uint(fabsf(alo - blo)) + 0x8000u;
                unsigned dhi = __float_as_uint(fabsf(ahi - bhi)) + 0x8000u;
                q[u] = __builtin_amdgcn_perm(dhi, dlo, 0x07060302u);
            }
            #pragma unroll
            for (int j = 0; j < 3; ++j) {
                uint2 wq; wq.x = q[2*j]; wq.y = q[2*j+1];
                *(uint2*)&rowp[24 + 4*j] = wq;
            }
        }
    };

    pack(0, 0);
    __syncthreads();

    for (int chunk = 0; chunk < SS/TC; ++chunk) {
        int cur = chunk & 1;
        if (chunk + 1 < SS/TC) pack(chunk + 1, cur ^ 1);

        short8 av[2][2];
        #pragma unroll
        for (int tt = 0; tt < 2; ++tt) {
            int arow = (wv*2 + tt)*16 + col;
            av[tt][0] = *(const short8*)&sAB[cur][arow*LSTR + quad*8];
            av[tt][1] = *(const short8*)&sAB[cur][arow*LSTR + 32 + quad*8];
        }
        float s0 = 0.f, s1 = 0.f;
        #pragma unroll
        for (int hf = 0; hf < 6; ++hf) {
            floatx4 a0 = {0.f,0.f,0.f,0.f}, a1 = {0.f,0.f,0.f,0.f};
            a0 = __builtin_amdgcn_mfma_f32_16x16x32_bf16(bfr[hf][0], av[0][0], a0, 0, 0, 0);
            a0 = __builtin_amdgcn_mfma_f32_16x16x32_bf16(bfr[hf][1], av[0][1], a0, 0, 0, 0);
            a1 = __builtin_amdgcn_mfma_f32_16x16x32_bf16(bfr[hf][0], av[1][0], a1, 0, 0, 0);
            a1 = __builtin_amdgcn_mfma_f32_16x16x32_bf16(bfr[hf][1], av[1][1], a1, 0, 0, 0);
            float w2v[4] = {w2q[hf].x, w2q[hf].y, w2q[hf].z, w2q[hf].w};
            #pragma unroll
            for (int r = 0; r < 4; ++r) {
                s0 = fmaf(fmaxf(a0[r], 0.f), w2v[r], s0);
                s1 = fmaf(fmaxf(a1[r], 0.f), w2v[r], s1);
            }
        }
        s0 += __shfl_xor(s0, 16, 64);  s0 += __shfl_xor(s0, 32, 64);
        s1 += __shfl_xor(s1, 16, 64);  s1 += __shfl_xor(s1, 32, 64);
        if (lane < 16) {
            sLog[chunk*TC + (wv*2 + 0)*16 + lane] = s0;
            sLog[chunk*TC + (wv*2 + 1)*16 + lane] = s1;
        }
        __syncthreads();
    }

    // ---- softmax ----
    float lv[4];
    #pragma unroll
    for (int i = 0; i < 4; ++i) {
        int t = tid + i*256;
        lv[i] = sLog[t] + (1.0f - mask[(size_t)(b<<10) + t]) * (-3.402823466e+38f);
    }
    float m = fmaxf(fmaxf(lv[0], lv[1]), fmaxf(lv[2], lv[3]));
    #pragma unroll
    for (int off = 32; off; off >>= 1) m = fmaxf(m, __shfl_down(m, off, 64));
    if (lane == 0) sRed[wv] = m;
    __syncthreads();
    float M = fmaxf(fmaxf(sRed[0], sRed[1]), fmaxf(sRed[2], sRed[3]));
    float e[4]; float ssum = 0.f;
    #pragma unroll
    for (int i = 0; i < 4; ++i) { e[i] = expf(lv[i] - M); ssum += e[i]; }
    #pragma unroll
    for (int off = 32; off; off >>= 1) ssum += __shfl_down(ssum, off, 64);
    __syncthreads();
    if (lane == 0) sRed[wv] = ssum;
    __syncthreads();
    float inv = 1.0f / (sRed[0] + sRed[1] + sRed[2] + sRed[3]);
    #pragma unroll
    for (int i = 0; i < 4; ++i)
        probs[(size_t)row*SS + tid + i*256] = f2bf(e[i] * inv);
}

// ---------------- Kernel 3: split-K=2 partial GEMM, 64x64 tile, gl16 -------
// A: [2048][K] bf16. BT: [768][K] bf16 (+ batch stride). P[z][2048][768] f32.
__global__ __launch_bounds__(256) void k_mgemm_p(
    const unsigned short* __restrict__ A,
    const unsigned short* __restrict__ BT,
    float* __restrict__ P,
    int K, int bt_bstride)
{
    __shared__ __align__(16) unsigned short sA[64*64];
    __shared__ __align__(16) unsigned short sB[64*64];
    int tid = threadIdx.x;
    int w = tid >> 6, lane = tid & 63;
    int quad = lane >> 4, col = lane & 15;

    int n0 = blockIdx.x * 64, m0 = blockIdx.y * 64;
    int z = blockIdx.z;
    int kslice = K >> 1;
    int k0 = z * kslice;
    int nk = kslice >> 6;
    const unsigned short* Bb = BT + (size_t)(m0 >> 10) * bt_bstride;

    int srow = lane >> 3;          // 0..7 within the 8-row staging group
    int skc  = (lane & 7) * 8;     // ushort offset within row

    floatx4 acc[4];
    #pragma unroll
    for (int nf = 0; nf < 4; ++nf) acc[nf] = (floatx4){0.f,0.f,0.f,0.f};

    for (int kb = 0; kb < nk; ++kb) {
        int kofs = k0 + kb*64;
        #pragma unroll
        for (int i = 0; i < 2; ++i) {
            int rbase = w*16 + i*8;
            gl16(A  + (size_t)(m0 + rbase + srow)*K + kofs + skc, &sA[rbase*64]);
            gl16(Bb + (size_t)(n0 + rbase + srow)*K + kofs + skc, &sB[rbase*64]);
        }
        __syncthreads();
        #pragma unroll
        for (int kt = 0; kt < 2; ++kt) {
            short8 av = *(const short8*)&sA[(w*16 + col)*64 + kt*32 + quad*8];
            #pragma unroll
            for (int nf = 0; nf < 4; ++nf) {
                short8 bv = *(const short8*)&sB[(nf*16 + col)*64 + kt*32 + quad*8];
                acc[nf] = __builtin_amdgcn_mfma_f32_16x16x32_bf16(av, bv, acc[nf], 0, 0, 0);
            }
        }
        __syncthreads();
    }

    float* Pz = P + (size_t)z*NRR*768;
    #pragma unroll
    for (int nf = 0; nf < 4; ++nf) {
        int n = n0 + nf*16 + col;
        #pragma unroll
        for (int r = 0; r < 4; ++r) {
            int m = w*16 + quad*4 + r;
            Pz[(size_t)(m0 + m)*768 + n] = acc[nf][r];
        }
    }
}

// ---------------- Kernel 4: reduce-epilogue (2 partials) -------------------
// MODE 0: msgin builder (ctx | hj | ctx*hj, bf16)
// MODE 1: Y1 = bf16(relu(sum + bias))    MODE 2: out = f32(alpha*(sum + bias))
template<int MODE>
__global__ __launch_bounds__(256) void k_epi(
    const float* __restrict__ P,
    const float* __restrict__ bias,
    const float* __restrict__ Hj,
    const float* __restrict__ alpha_p,
    void* __restrict__ Cout)
{
    int idx = blockIdx.x*256 + threadIdx.x;     // 0 .. 2048*192-1
    int g = idx / 192, c = (idx % 192) * 4;
    float4 v0 = *(const float4*)(P + (size_t)g*768 + c);
    float4 v1 = *(const float4*)(P + (size_t)NRR*768 + (size_t)g*768 + c);
    float v[4] = {v0.x+v1.x, v0.y+v1.y, v0.z+v1.z, v0.w+v1.w};
    if (MODE == 0) {
        float4 h4 = *(const float4*)(Hj + (size_t)g*HH + c);
        float hj[4] = {h4.x, h4.y, h4.z, h4.w};
        unsigned short* msgin = (unsigned short*)Cout;
        uint2 wc, wh, wp;
        wc.x = pack2(v[0], v[1]);        wc.y = pack2(v[2], v[3]);
        wh.x = pack2(hj[0], hj[1]);      wh.y = pack2(hj[2], hj[3]);
        wp.x = pack2(v[0]*hj[0], v[1]*hj[1]);
        wp.y = pack2(v[2]*hj[2], v[3]*hj[3]);
        *(uint2*)&msgin[(size_t)g*VINN + c]        = wc;
        *(uint2*)&msgin[(size_t)g*VINN + HH + c]   = wh;
        *(uint2*)&msgin[(size_t)g*VINN + 2*HH + c] = wp;
    } else if (MODE == 1) {
        float4 b4 = *(const float4*)(bias + c);
        uint2 wy;
        wy.x = pack2(fmaxf(v[0]+b4.x, 0.f), fmaxf(v[1]+b4.y, 0.f));
        wy.y = pack2(fmaxf(v[2]+b4.z, 0.f), fmaxf(v[3]+b4.w, 0.f));
        *(uint2*)&((unsigned short*)Cout)[(size_t)g*VHIDD + c] = wy;
    } else {
        float a = alpha_p[0];
        float4 b4 = *(const float4*)(bias + c);
        float4 o;
        o.x = a*(v[0]+b4.x); o.y = a*(v[1]+b4.y);
        o.z = a*(v[2]+b4.z); o.w = a*(v[3]+b4.w);
        *(float4*)&((float*)Cout)[(size_t)g*HH + c] = o;
    }
}

extern "C" void kernel_launch(void* const* d_in, const int* in_sizes, int n_in,
                              void* d_out, int out_size, void* d_ws, size_t ws_size,
                              hipStream_t stream)
{
    const float* Hj   = (const float*)d_in[0];
    const float* Hi   = (const float*)d_in[1];
    const float* mask = (const float*)d_in[2];
    const float* Wpj  = (const float*)d_in[3];
    const float* Wpi  = (const float*)d_in[4];
    const float* W1   = (const float*)d_in[5];
    const float* b1   = (const float*)d_in[6];
    const float* W2   = (const float*)d_in[7];
    const float* Wv1  = (const float*)d_in[9];
    const float* bv1  = (const float*)d_in[10];
    const float* Wv2  = (const float*)d_in[11];
    const float* bv2  = (const float*)d_in[12];
    const float* alpha = (const float*)d_in[13];
    float* out = (float*)d_out;

    const int NR = NRR;                   // 2048
    char* p = (char*)d_ws;
    auto alloc = [&](size_t bytes) {
        char* r = p; p += (bytes + 255) & ~(size_t)255; return r;
    };
    unsigned* Zjp          = (unsigned*)alloc((size_t)NR*12*4);
    unsigned* Zip          = (unsigned*)alloc((size_t)NR*12*4);
    unsigned short* probsb = (unsigned short*)alloc((size_t)NR*SS*2);
    unsigned short* HiT    = (unsigned short*)alloc((size_t)BB*HH*SS*2);
    unsigned short* Wv1T   = (unsigned short*)alloc((size_t)VHIDD*VINN*2);
    unsigned short* Wv2T   = (unsigned short*)alloc((size_t)HH*VHIDD*2);
    unsigned short* msginb = (unsigned short*)alloc((size_t)NR*VINN*2);
    unsigned short* Y1b    = (unsigned short*)alloc((size_t)NR*VHIDD*2);
    float* Part            = (float*)alloc((size_t)2*NR*768*4);

    k_tconv<<<dim3(VHIDD/32, VINN/32, 1), 256, 0, stream>>>(Wv1, Wv1T, VINN, VHIDD);
    k_tconv<<<dim3(HH/32, VHIDD/32, 1), 256, 0, stream>>>(Wv2, Wv2T, VHIDD, HH);
    k_tconv<<<dim3(HH/32, SS/32, BB), 256, 0, stream>>>(Hi, HiT, SS, HH);
    k_zproj<<<2*NR/64, 256, 0, stream>>>(Hj, Hi, Wpj, Wpi, Zjp, Zip);
    k_attn<<<NR, 256, 0, stream>>>(Zjp, Zip, W1, b1, W2, mask, probsb);

    const int EPI_GRID = NR*192/256;      // 1536

    // ctx GEMM: M=2048 (batch via bt stride), N=768, K=1024, split 2
    k_mgemm_p<<<dim3(HH/64, NR/64, 2), 256, 0, stream>>>(
        probsb, HiT, Part, SS, HH*SS);
    k_epi<0><<<EPI_GRID, 256, 0, stream>>>(Part, nullptr, Hj, alpha, msginb);

    // MLP GEMM1: K=2304, split 2
    k_mgemm_p<<<dim3(VHIDD/64, NR/64, 2), 256, 0, stream>>>(
        msginb, Wv1T, Part, VINN, 0);
    k_epi<1><<<EPI_GRID, 256, 0, stream>>>(Part, bv1, nullptr, alpha, Y1b);

    // MLP GEMM2: K=768, split 2
    k_mgemm_p<<<dim3(HH/64, NR/64, 2), 256, 0, stream>>>(
        Y1b, Wv2T, Part, VHIDD, 0);
    k_epi<2><<<EPI_GRID, 256, 0, stream>>>(Part, bv2, nullptr, alpha, out);
}

// Round 11
// 207.504 us; speedup vs baseline: 2.7661x; 1.0453x over previous
//
#include <hip/hip_runtime.h>
#include <math.h>

#define BB   2
#define SS   1024
#define HH   768
#define DD   24
#define HIDD 96
#define VINN 2304   // 3*H
#define VHIDD 768
#define NRR  2048   // BB*SS

typedef __attribute__((ext_vector_type(8))) short short8;
typedef __attribute__((ext_vector_type(4))) float floatx4;

static __device__ inline unsigned short f2bf(float x) {
    unsigned int u = __float_as_uint(x);
    u = (u + 0x7FFFu + ((u >> 16) & 1u)) >> 16;
    return (unsigned short)u;
}
static __device__ inline unsigned int pack2(float a, float b) {
    return (unsigned int)f2bf(a) | ((unsigned int)f2bf(b) << 16);
}

// async global -> LDS, 16 B per lane; LDS dest = wave-uniform base + lane*16
static __device__ inline void gl16(const unsigned short* g, unsigned short* l) {
    __builtin_amdgcn_global_load_lds(
        (const __attribute__((address_space(1))) unsigned int*)g,
        (__attribute__((address_space(3))) unsigned int*)l,
        16, 0, 0);
}

// ---------------- Kernel 0: fused prep --------------------------------------
// blocks 0..63: Z projections (MFMA), packed-bf16 output.
// blocks 64..: f32->bf16 transpose-convert for Wv1T / Wv2T / HiT.
__global__ __launch_bounds__(256) void k_prep(
    const float* __restrict__ Hj, const float* __restrict__ Hi,
    const float* __restrict__ Wpj, const float* __restrict__ Wpi,
    const float* __restrict__ Wv1, const float* __restrict__ Wv2,
    unsigned* __restrict__ Zjp, unsigned* __restrict__ Zip,
    unsigned short* __restrict__ Wv1T, unsigned short* __restrict__ Wv2T,
    unsigned short* __restrict__ HiT)
{
    __shared__ __align__(16) unsigned short sAz[64][72];
    __shared__ __align__(16) unsigned short sBTz[32][72];
    __shared__ float tile[32][33];
    int bid = blockIdx.x;
    int tid = threadIdx.x;

    if (bid < 64) {
        // ---------------- zproj ----------------
        int w = tid >> 6, lane = tid & 63;
        int quad = lane >> 4, col = lane & 15;
        int m0 = bid * 64;
        bool isJ = (m0 < NRR);
        const float* src = isJ ? Hj : Hi;
        const float* Wp  = isJ ? Wpj : Wpi;
        unsigned* Zp     = isJ ? Zjp : Zip;
        int rowbase = isJ ? m0 : (m0 - NRR);

        floatx4 acc[2];
        acc[0] = (floatx4){0.f,0.f,0.f,0.f};
        acc[1] = (floatx4){0.f,0.f,0.f,0.f};

        for (int kb = 0; kb < HH; kb += 64) {
            #pragma unroll
            for (int i = 0; i < 4; ++i) {
                int f4 = tid + i*256;
                int r = f4 >> 4, c4 = f4 & 15;
                float4 v = *(const float4*)(src + (size_t)(rowbase + r)*HH + kb + c4*4);
                uint2 pkt; pkt.x = pack2(v.x, v.y); pkt.y = pack2(v.z, v.w);
                *(uint2*)&sAz[r][c4*4] = pkt;
            }
            {
                const float* wsrc = Wp + (size_t)kb*DD;
                #pragma unroll
                for (int i = 0; i < 6; ++i) {
                    int idx = tid + i*256;
                    int k = idx / DD, n = idx % DD;
                    sBTz[n][k] = f2bf(wsrc[idx]);
                }
            }
            __syncthreads();
            #pragma unroll
            for (int kt = 0; kt < 2; ++kt) {
                short8 av = *(const short8*)&sAz[w*16 + col][kt*32 + quad*8];
                #pragma unroll
                for (int nt = 0; nt < 2; ++nt) {
                    short8 bv = *(const short8*)&sBTz[nt*16 + col][kt*32 + quad*8];
                    acc[nt] = __builtin_amdgcn_mfma_f32_16x16x32_bf16(av, bv, acc[nt], 0, 0, 0);
                }
            }
            __syncthreads();
        }
        #pragma unroll
        for (int nt = 0; nt < 2; ++nt) {
            #pragma unroll
            for (int r = 0; r < 4; ++r) {
                float v = acc[nt][r];
                float vn = __shfl_xor(v, 1, 64);
                int n = nt*16 + col;
                if (!(col & 1) && n < DD) {
                    int m = w*16 + quad*4 + r;
                    Zp[(size_t)(rowbase + m)*12 + (n >> 1)] = pack2(v, vn);
                }
            }
        }
        return;
    }

    // ---------------- tconv segments ----------------
    int b2 = bid - 64;
    const float* in; unsigned short* out; int R, C, r0, c0;
    if (b2 < 1728) {                 // Wv1T: [2304][768] -> [768][2304]
        in = Wv1; out = Wv1T; R = VINN; C = VHIDD;
        c0 = (b2 % 24) * 32; r0 = (b2 / 24) * 32;
    } else if (b2 < 2304) {          // Wv2T: [768][768] -> [768][768]
        int t = b2 - 1728;
        in = Wv2; out = Wv2T; R = VHIDD; C = HH;
        c0 = (t % 24) * 32; r0 = (t / 24) * 32;
    } else {                          // HiT: per batch [1024][768] -> [768][1024]
        int t = b2 - 2304;
        int z = t / 768; t %= 768;
        in = Hi + (size_t)z*SS*HH; out = HiT + (size_t)z*HH*SS;
        R = SS; C = HH;
        c0 = (t % 24) * 32; r0 = (t / 24) * 32;
    }
    int tc = tid & 31, tr = tid >> 5;
    #pragma unroll
    for (int i = 0; i < 4; ++i)
        tile[tr + i*8][tc] = in[(size_t)(r0 + tr + i*8)*C + c0 + tc];
    __syncthreads();
    #pragma unroll
    for (int i = 0; i < 4; ++i)
        out[(size_t)(c0 + tr + i*8)*R + r0 + tc] = f2bf(tile[tc][tr + i*8]);
}

// ---------------- Kernel 2: MFMA logits + softmax -> probs (bf16) ----------
#define LSTR 72
#define TC 128
__global__ __launch_bounds__(256) void k_attn(
    const unsigned* __restrict__ Zjp, const unsigned* __restrict__ Zip,
    const float* __restrict__ W1, const float* __restrict__ b1,
    const float* __restrict__ W2,
    const float* __restrict__ mask, unsigned short* __restrict__ probs)
{
    int row = blockIdx.x;       // b*S + s
    int b = row >> 10;
    int tid = threadIdx.x;
    int lane = tid & 63, wv = tid >> 6;
    int quad = lane >> 4, col = lane & 15;

    __shared__ __align__(16) unsigned short sAB[2][TC*LSTR]; // B-build in [0], then A dbuf
    __shared__ __align__(16) float sLog[SS];
    __shared__ unsigned sZjp[12];
    __shared__ float sW2[HIDD];
    __shared__ float sRed[4];

    if (tid < 12) sZjp[tid] = Zjp[(size_t)row*12 + tid];
    if (tid < HIDD) sW2[tid] = W2[tid];
    __syncthreads();

    if (tid < HIDD) {
        int h = tid;
        float zj[24];
        #pragma unroll
        for (int u = 0; u < 12; ++u) {
            unsigned z = sZjp[u];
            zj[2*u]   = __uint_as_float(z << 16);
            zj[2*u+1] = __uint_as_float(z & 0xffff0000u);
        }
        float tj = b1[h];
        #pragma unroll
        for (int d = 0; d < DD; ++d) tj = fmaf(zj[d], W1[d*HIDD + h], tj);
        unsigned short* rowp = &sAB[0][h*LSTR];
        #pragma unroll
        for (int d = 0; d < DD; ++d)
            rowp[d] = f2bf(fmaf(zj[d], W1[(48+d)*HIDD + h], W1[(24+d)*HIDD + h]));
        #pragma unroll
        for (int d = 0; d < DD; ++d)
            rowp[24+d] = f2bf(W1[(72+d)*HIDD + h]);
        rowp[48] = f2bf(tj);
        #pragma unroll
        for (int k = 49; k < 64; ++k) rowp[k] = 0;
    }
    __syncthreads();

    short8 bfr[6][2];
    #pragma unroll
    for (int nf = 0; nf < 6; ++nf)
        #pragma unroll
        for (int kt = 0; kt < 2; ++kt)
            bfr[nf][kt] = *(const short8*)&sAB[0][(nf*16 + col)*LSTR + kt*32 + quad*8];
    float4 w2q[6];
    #pragma unroll
    for (int nf = 0; nf < 6; ++nf)
        w2q[nf] = *(const float4*)&sW2[nf*16 + quad*4];
    __syncthreads();   // sAB now reused as A double-buffer

    {
        int r = tid >> 1, bf = tid & 1;
        unsigned short* rowp = &sAB[bf][r*LSTR];
        uint4 w0; w0.x = 0x3F80u; w0.y = 0; w0.z = 0; w0.w = 0;
        *(uint4*)&rowp[48] = w0;
        uint4 zz; zz.x = 0; zz.y = 0; zz.z = 0; zz.w = 0;
        *(uint4*)&rowp[56] = zz;
    }

    int t_loc = tid >> 1, hh = tid & 1;
    const unsigned* zbase = Zip + (size_t)(b << 10) * 12;

    auto pack = [&](int chunk, int bf) {
        int t = chunk*TC + t_loc;
        const unsigned* zr = zbase + (size_t)t*12;
        unsigned short* rowp = &sAB[bf][t_loc*LSTR];
        uint4 first = *(const uint4*)(zr + hh*4);
        *(uint4*)&rowp[hh*8] = first;
        uint2 ext; ext.x = 0; ext.y = 0;
        if (hh) {
            uint4 second = *(const uint4*)(zr + 8);
            *(uint4*)&rowp[16] = second;
            unsigned myz[6] = {first.z, first.w, second.x, second.y, second.z, second.w};
            unsigned q[6];
            #pragma unroll
            for (int u = 0; u < 6; ++u) {
                unsigned za = sZjp[6 + u], zb = myz[u];
                float alo = __uint_as_float(za << 16);
                float ahi = __uint_as_float(za & 0xffff0000u);
                float blo = __uint_as_float(zb << 16);
                float bhi = __uint_as_float(zb & 0xffff0000u);
                unsigned dlo = __float_as_uint(fabsf(alo - blo)) + 0x8000u;
                unsigned dhi = __float_as_uint(fabsf(ahi - bhi)) + 0x8000u;
                q[u] = __builtin_amdgcn_perm(dhi, dlo, 0x07060302u);
            }
            #pragma unroll
            for (int j = 0; j < 3; ++j) {
                uint2 wq; wq.x = q[2*j]; wq.y = q[2*j+1];
                *(uint2*)&rowp[36 + 4*j] = wq;
            }
        } else {
            ext = *(const uint2*)(zr + 4);
            unsigned myz[6] = {first.x, first.y, first.z, first.w, ext.x, ext.y};
            unsigned q[6];
            #pragma unroll
            for (int u = 0; u < 6; ++u) {
                unsigned za = sZjp[u], zb = myz[u];
                float alo = __uint_as_float(za << 16);
                float ahi = __uint_as_float(za & 0xffff0000u);
                float blo = __uint_as_float(zb << 16);
                float bhi = __uint_as_float(zb & 0xffff0000u);
                unsigned dlo = __float_as_uint(fabsf(alo - blo)) + 0x8000u;
                unsigned dhi = __float_as_uint(fabsf(ahi - bhi)) + 0x8000u;
                q[u] = __builtin_amdgcn_perm(dhi, dlo, 0x07060302u);
            }
            #pragma unroll
            for (int j = 0; j < 3; ++j) {
                uint2 wq; wq.x = q[2*j]; wq.y = q[2*j+1];
                *(uint2*)&rowp[24 + 4*j] = wq;
            }
        }
    };

    pack(0, 0);
    __syncthreads();

    for (int chunk = 0; chunk < SS/TC; ++chunk) {
        int cur = chunk & 1;
        if (chunk + 1 < SS/TC) pack(chunk + 1, cur ^ 1);

        short8 av[2][2];
        #pragma unroll
        for (int tt = 0; tt < 2; ++tt) {
            int arow = (wv*2 + tt)*16 + col;
            av[tt][0] = *(const short8*)&sAB[cur][arow*LSTR + quad*8];
            av[tt][1] = *(const short8*)&sAB[cur][arow*LSTR + 32 + quad*8];
        }
        float s0 = 0.f, s1 = 0.f;
        #pragma unroll
        for (int hf = 0; hf < 6; ++hf) {
            floatx4 a0 = {0.f,0.f,0.f,0.f}, a1 = {0.f,0.f,0.f,0.f};
            a0 = __builtin_amdgcn_mfma_f32_16x16x32_bf16(bfr[hf][0], av[0][0], a0, 0, 0, 0);
            a0 = __builtin_amdgcn_mfma_f32_16x16x32_bf16(bfr[hf][1], av[0][1], a0, 0, 0, 0);
            a1 = __builtin_amdgcn_mfma_f32_16x16x32_bf16(bfr[hf][0], av[1][0], a1, 0, 0, 0);
            a1 = __builtin_amdgcn_mfma_f32_16x16x32_bf16(bfr[hf][1], av[1][1], a1, 0, 0, 0);
            float w2v[4] = {w2q[hf].x, w2q[hf].y, w2q[hf].z, w2q[hf].w};
            #pragma unroll
            for (int r = 0; r < 4; ++r) {
                s0 = fmaf(fmaxf(a0[r], 0.f), w2v[r], s0);
                s1 = fmaf(fmaxf(a1[r], 0.f), w2v[r], s1);
            }
        }
        s0 += __shfl_xor(s0, 16, 64);  s0 += __shfl_xor(s0, 32, 64);
        s1 += __shfl_xor(s1, 16, 64);  s1 += __shfl_xor(s1, 32, 64);
        if (lane < 16) {
            sLog[chunk*TC + (wv*2 + 0)*16 + lane] = s0;
            sLog[chunk*TC + (wv*2 + 1)*16 + lane] = s1;
        }
        __syncthreads();
    }

    // ---- softmax ----
    float lv[4];
    #pragma unroll
    for (int i = 0; i < 4; ++i) {
        int t = tid + i*256;
        lv[i] = sLog[t] + (1.0f - mask[(size_t)(b<<10) + t]) * (-3.402823466e+38f);
    }
    float m = fmaxf(fmaxf(lv[0], lv[1]), fmaxf(lv[2], lv[3]));
    #pragma unroll
    for (int off = 32; off; off >>= 1) m = fmaxf(m, __shfl_down(m, off, 64));
    if (lane == 0) sRed[wv] = m;
    __syncthreads();
    float M = fmaxf(fmaxf(sRed[0], sRed[1]), fmaxf(sRed[2], sRed[3]));
    float e[4]; float ssum = 0.f;
    #pragma unroll
    for (int i = 0; i < 4; ++i) { e[i] = expf(lv[i] - M); ssum += e[i]; }
    #pragma unroll
    for (int off = 32; off; off >>= 1) ssum += __shfl_down(ssum, off, 64);
    __syncthreads();
    if (lane == 0) sRed[wv] = ssum;
    __syncthreads();
    float inv = 1.0f / (sRed[0] + sRed[1] + sRed[2] + sRed[3]);
    #pragma unroll
    for (int i = 0; i < 4; ++i)
        probs[(size_t)row*SS + tid + i*256] = f2bf(e[i] * inv);
}

// ---------------- Kernel 3: split-K=2 partial GEMM, 64x64 tile, gl16 -------
// (used for MLP1 only, K=2304). P[z][2048][768] f32.
__global__ __launch_bounds__(256) void k_mgemm_p(
    const unsigned short* __restrict__ A,
    const unsigned short* __restrict__ BT,
    float* __restrict__ P,
    int K, int bt_bstride)
{
    __shared__ __align__(16) unsigned short sA[64*64];
    __shared__ __align__(16) unsigned short sB[64*64];
    int tid = threadIdx.x;
    int w = tid >> 6, lane = tid & 63;
    int quad = lane >> 4, col = lane & 15;

    int n0 = blockIdx.x * 64, m0 = blockIdx.y * 64;
    int z = blockIdx.z;
    int kslice = K >> 1;
    int k0 = z * kslice;
    int nk = kslice >> 6;
    const unsigned short* Bb = BT + (size_t)(m0 >> 10) * bt_bstride;

    int srow = lane >> 3;
    int skc  = (lane & 7) * 8;

    floatx4 acc[4];
    #pragma unroll
    for (int nf = 0; nf < 4; ++nf) acc[nf] = (floatx4){0.f,0.f,0.f,0.f};

    for (int kb = 0; kb < nk; ++kb) {
        int kofs = k0 + kb*64;
        #pragma unroll
        for (int i = 0; i < 2; ++i) {
            int rbase = w*16 + i*8;
            gl16(A  + (size_t)(m0 + rbase + srow)*K + kofs + skc, &sA[rbase*64]);
            gl16(Bb + (size_t)(n0 + rbase + srow)*K + kofs + skc, &sB[rbase*64]);
        }
        __syncthreads();
        #pragma unroll
        for (int kt = 0; kt < 2; ++kt) {
            short8 av = *(const short8*)&sA[(w*16 + col)*64 + kt*32 + quad*8];
            #pragma unroll
            for (int nf = 0; nf < 4; ++nf) {
                short8 bv = *(const short8*)&sB[(nf*16 + col)*64 + kt*32 + quad*8];
                acc[nf] = __builtin_amdgcn_mfma_f32_16x16x32_bf16(av, bv, acc[nf], 0, 0, 0);
            }
        }
        __syncthreads();
    }

    float* Pz = P + (size_t)z*NRR*768;
    #pragma unroll
    for (int nf = 0; nf < 4; ++nf) {
        int n = n0 + nf*16 + col;
        #pragma unroll
        for (int r = 0; r < 4; ++r) {
            int m = w*16 + quad*4 + r;
            Pz[(size_t)(m0 + m)*768 + n] = acc[nf][r];
        }
    }
}

// ---------------- Kernel 3b: no-split GEMM, 64Mx32N, fused epilogue --------
// MODE 0: msgin builder (ctx | hj | ctx*hj, bf16)
// MODE 2: out = f32(alpha*(acc + bias))
template<int MODE>
__global__ __launch_bounds__(256) void k_mgemm_nf(
    const unsigned short* __restrict__ A,
    const unsigned short* __restrict__ BT,
    const float* __restrict__ bias,
    const float* __restrict__ Hj,
    const float* __restrict__ alpha_p,
    void* __restrict__ Cout,
    int K, int bt_bstride)
{
    __shared__ __align__(16) unsigned short sA[64*64];
    __shared__ __align__(16) unsigned short sB[32*64];
    int tid = threadIdx.x;
    int w = tid >> 6, lane = tid & 63;
    int quad = lane >> 4, col = lane & 15;

    int n0 = blockIdx.x * 32, m0 = blockIdx.y * 64;
    int nk = K >> 6;
    const unsigned short* Bb = BT + (size_t)(m0 >> 10) * bt_bstride;

    int srow = lane >> 3;
    int skc  = (lane & 7) * 8;

    floatx4 acc[2];
    acc[0] = (floatx4){0.f,0.f,0.f,0.f};
    acc[1] = (floatx4){0.f,0.f,0.f,0.f};

    for (int kb = 0; kb < nk; ++kb) {
        int kofs = kb*64;
        gl16(A  + (size_t)(m0 + w*16     + srow)*K + kofs + skc, &sA[(w*16)*64]);
        gl16(A  + (size_t)(m0 + w*16 + 8 + srow)*K + kofs + skc, &sA[(w*16 + 8)*64]);
        gl16(Bb + (size_t)(n0 + w*8      + srow)*K + kofs + skc, &sB[(w*8)*64]);
        __syncthreads();
        #pragma unroll
        for (int kt = 0; kt < 2; ++kt) {
            short8 av = *(const short8*)&sA[(w*16 + col)*64 + kt*32 + quad*8];
            #pragma unroll
            for (int nf = 0; nf < 2; ++nf) {
                short8 bv = *(const short8*)&sB[(nf*16 + col)*64 + kt*32 + quad*8];
                acc[nf] = __builtin_amdgcn_mfma_f32_16x16x32_bf16(av, bv, acc[nf], 0, 0, 0);
            }
        }
        __syncthreads();
    }

    float alpha = (MODE == 2) ? alpha_p[0] : 1.0f;
    #pragma unroll
    for (int nf = 0; nf < 2; ++nf) {
        int n = n0 + nf*16 + col;
        #pragma unroll
        for (int r = 0; r < 4; ++r) {
            int m = w*16 + quad*4 + r;
            size_t g = (size_t)(m0 + m);
            float v = acc[nf][r];
            if (MODE == 0) {
                float hj = Hj[g*HH + n];
                unsigned short* msgin = (unsigned short*)Cout;
                msgin[g*VINN + n]        = f2bf(v);
                msgin[g*VINN + HH + n]   = f2bf(hj);
                msgin[g*VINN + 2*HH + n] = f2bf(v*hj);
            } else {
                ((float*)Cout)[g*HH + n] = alpha*(v + bias[n]);
            }
        }
    }
}

// ---------------- Kernel 4: reduce-epilogue (2 partials) — MLP1 only -------
__global__ __launch_bounds__(256) void k_epi1(
    const float* __restrict__ P,
    const float* __restrict__ bias,
    unsigned short* __restrict__ Y1)
{
    int idx = blockIdx.x*256 + threadIdx.x;     // 0 .. 2048*192-1
    int g = idx / 192, c = (idx % 192) * 4;
    float4 v0 = *(const float4*)(P + (size_t)g*768 + c);
    float4 v1 = *(const float4*)(P + (size_t)NRR*768 + (size_t)g*768 + c);
    float4 b4 = *(const float4*)(bias + c);
    uint2 wy;
    wy.x = pack2(fmaxf(v0.x+v1.x+b4.x, 0.f), fmaxf(v0.y+v1.y+b4.y, 0.f));
    wy.y = pack2(fmaxf(v0.z+v1.z+b4.z, 0.f), fmaxf(v0.w+v1.w+b4.w, 0.f));
    *(uint2*)&Y1[(size_t)g*VHIDD + c] = wy;
}

extern "C" void kernel_launch(void* const* d_in, const int* in_sizes, int n_in,
                              void* d_out, int out_size, void* d_ws, size_t ws_size,
                              hipStream_t stream)
{
    const float* Hj   = (const float*)d_in[0];
    const float* Hi   = (const float*)d_in[1];
    const float* mask = (const float*)d_in[2];
    const float* Wpj  = (const float*)d_in[3];
    const float* Wpi  = (const float*)d_in[4];
    const float* W1   = (const float*)d_in[5];
    const float* b1   = (const float*)d_in[6];
    const float* W2   = (const float*)d_in[7];
    const float* Wv1  = (const float*)d_in[9];
    const float* bv1  = (const float*)d_in[10];
    const float* Wv2  = (const float*)d_in[11];
    const float* bv2  = (const float*)d_in[12];
    const float* alpha = (const float*)d_in[13];
    float* out = (float*)d_out;

    const int NR = NRR;                   // 2048
    char* p = (char*)d_ws;
    auto alloc = [&](size_t bytes) {
        char* r = p; p += (bytes + 255) & ~(size_t)255; return r;
    };
    unsigned* Zjp          = (unsigned*)alloc((size_t)NR*12*4);
    unsigned* Zip          = (unsigned*)alloc((size_t)NR*12*4);
    unsigned short* probsb = (unsigned short*)alloc((size_t)NR*SS*2);
    unsigned short* HiT    = (unsigned short*)alloc((size_t)BB*HH*SS*2);
    unsigned short* Wv1T   = (unsigned short*)alloc((size_t)VHIDD*VINN*2);
    unsigned short* Wv2T   = (unsigned short*)alloc((size_t)HH*VHIDD*2);
    unsigned short* msginb = (unsigned short*)alloc((size_t)NR*VINN*2);
    unsigned short* Y1b    = (unsigned short*)alloc((size_t)NR*VHIDD*2);
    float* Part            = (float*)alloc((size_t)2*NR*768*4);

    // prep: 64 zproj blocks + 1728 (Wv1T) + 576 (Wv2T) + 1536 (HiT) tconv blocks
    k_prep<<<64 + 1728 + 576 + 1536, 256, 0, stream>>>(
        Hj, Hi, Wpj, Wpi, Wv1, Wv2, Zjp, Zip, Wv1T, Wv2T, HiT);

    k_attn<<<NR, 256, 0, stream>>>(Zjp, Zip, W1, b1, W2, mask, probsb);

    // ctx GEMM: M=2048 (batch via bt stride), N=768, K=1024, no split,
    // fused msgin epilogue. 24 x 32 = 768 blocks.
    k_mgemm_nf<0><<<dim3(HH/32, NR/64), 256, 0, stream>>>(
        probsb, HiT, nullptr, Hj, alpha, msginb, SS, HH*SS);

    // MLP GEMM1: K=2304, split 2 + reduce-epilogue
    k_mgemm_p<<<dim3(VHIDD/64, NR/64, 2), 256, 0, stream>>>(
        msginb, Wv1T, Part, VINN, 0);
    k_epi1<<<NR*192/256, 256, 0, stream>>>(Part, bv1, Y1b);

    // MLP GEMM2: K=768, no split, fused f32 epilogue. 768 blocks.
    k_mgemm_nf<2><<<dim3(HH/32, NR/64), 256, 0, stream>>>(
        Y1b, Wv2T, bv2, nullptr, alpha, out, VHIDD, 0);
}

// Round 12
// 201.851 us; speedup vs baseline: 2.8435x; 1.0280x over previous
//
#include <hip/hip_runtime.h>
#include <math.h>

#define BB   2
#define SS   1024
#define HH   768
#define DD   24
#define HIDD 96
#define VINN 2304   // 3*H
#define VHIDD 768
#define NRR  2048   // BB*SS

typedef __attribute__((ext_vector_type(8))) short short8;
typedef __attribute__((ext_vector_type(4))) float floatx4;

static __device__ inline unsigned short f2bf(float x) {
    unsigned int u = __float_as_uint(x);
    u = (u + 0x7FFFu + ((u >> 16) & 1u)) >> 16;
    return (unsigned short)u;
}
static __device__ inline unsigned int pack2(float a, float b) {
    return (unsigned int)f2bf(a) | ((unsigned int)f2bf(b) << 16);
}

// async global -> LDS, 16 B per lane; LDS dest = wave-uniform base + lane*16
static __device__ inline void gl16(const unsigned short* g, unsigned short* l) {
    __builtin_amdgcn_global_load_lds(
        (const __attribute__((address_space(1))) unsigned int*)g,
        (__attribute__((address_space(3))) unsigned int*)l,
        16, 0, 0);
}

// ---------------- Kernel 0: fused prep --------------------------------------
// blocks 0..63: Z projections (MFMA), packed-bf16 output.
// blocks 64..: f32->bf16 transpose-convert for Wv1T / Wv2T / HiT.
__global__ __launch_bounds__(256) void k_prep(
    const float* __restrict__ Hj, const float* __restrict__ Hi,
    const float* __restrict__ Wpj, const float* __restrict__ Wpi,
    const float* __restrict__ Wv1, const float* __restrict__ Wv2,
    unsigned* __restrict__ Zjp, unsigned* __restrict__ Zip,
    unsigned short* __restrict__ Wv1T, unsigned short* __restrict__ Wv2T,
    unsigned short* __restrict__ HiT)
{
    __shared__ __align__(16) unsigned short sAz[64][72];
    __shared__ __align__(16) unsigned short sBTz[32][72];
    __shared__ float tile[32][33];
    int bid = blockIdx.x;
    int tid = threadIdx.x;

    if (bid < 64) {
        // ---------------- zproj ----------------
        int w = tid >> 6, lane = tid & 63;
        int quad = lane >> 4, col = lane & 15;
        int m0 = bid * 64;
        bool isJ = (m0 < NRR);
        const float* src = isJ ? Hj : Hi;
        const float* Wp  = isJ ? Wpj : Wpi;
        unsigned* Zp     = isJ ? Zjp : Zip;
        int rowbase = isJ ? m0 : (m0 - NRR);

        floatx4 acc[2];
        acc[0] = (floatx4){0.f,0.f,0.f,0.f};
        acc[1] = (floatx4){0.f,0.f,0.f,0.f};

        for (int kb = 0; kb < HH; kb += 64) {
            #pragma unroll
            for (int i = 0; i < 4; ++i) {
                int f4 = tid + i*256;
                int r = f4 >> 4, c4 = f4 & 15;
                float4 v = *(const float4*)(src + (size_t)(rowbase + r)*HH + kb + c4*4);
                uint2 pkt; pkt.x = pack2(v.x, v.y); pkt.y = pack2(v.z, v.w);
                *(uint2*)&sAz[r][c4*4] = pkt;
            }
            {
                const float* wsrc = Wp + (size_t)kb*DD;
                #pragma unroll
                for (int i = 0; i < 6; ++i) {
                    int idx = tid + i*256;
                    int k = idx / DD, n = idx % DD;
                    sBTz[n][k] = f2bf(wsrc[idx]);
                }
            }
            __syncthreads();
            #pragma unroll
            for (int kt = 0; kt < 2; ++kt) {
                short8 av = *(const short8*)&sAz[w*16 + col][kt*32 + quad*8];
                #pragma unroll
                for (int nt = 0; nt < 2; ++nt) {
                    short8 bv = *(const short8*)&sBTz[nt*16 + col][kt*32 + quad*8];
                    acc[nt] = __builtin_amdgcn_mfma_f32_16x16x32_bf16(av, bv, acc[nt], 0, 0, 0);
                }
            }
            __syncthreads();
        }
        #pragma unroll
        for (int nt = 0; nt < 2; ++nt) {
            #pragma unroll
            for (int r = 0; r < 4; ++r) {
                float v = acc[nt][r];
                float vn = __shfl_xor(v, 1, 64);
                int n = nt*16 + col;
                if (!(col & 1) && n < DD) {
                    int m = w*16 + quad*4 + r;
                    Zp[(size_t)(rowbase + m)*12 + (n >> 1)] = pack2(v, vn);
                }
            }
        }
        return;
    }

    // ---------------- tconv segments ----------------
    int b2 = bid - 64;
    const float* in; unsigned short* out; int R, C, r0, c0;
    if (b2 < 1728) {                 // Wv1T: [2304][768] -> [768][2304]
        in = Wv1; out = Wv1T; R = VINN; C = VHIDD;
        c0 = (b2 % 24) * 32; r0 = (b2 / 24) * 32;
    } else if (b2 < 2304) {          // Wv2T: [768][768] -> [768][768]
        int t = b2 - 1728;
        in = Wv2; out = Wv2T; R = VHIDD; C = HH;
        c0 = (t % 24) * 32; r0 = (t / 24) * 32;
    } else {                          // HiT: per batch [1024][768] -> [768][1024]
        int t = b2 - 2304;
        int z = t / 768; t %= 768;
        in = Hi + (size_t)z*SS*HH; out = HiT + (size_t)z*HH*SS;
        R = SS; C = HH;
        c0 = (t % 24) * 32; r0 = (t / 24) * 32;
    }
    int tc = tid & 31, tr = tid >> 5;
    #pragma unroll
    for (int i = 0; i < 4; ++i)
        tile[tr + i*8][tc] = in[(size_t)(r0 + tr + i*8)*C + c0 + tc];
    __syncthreads();
    #pragma unroll
    for (int i = 0; i < 4; ++i)
        out[(size_t)(c0 + tr + i*8)*R + r0 + tc] = f2bf(tile[tc][tr + i*8]);
}

// ---------------- Kernel 2: MFMA logits + softmax -> probs (bf16) ----------
// TC=64 chunks, double-buffered (23 KB LDS -> ~6 blocks/CU).
// A[t,k]: 0..23 = Zi, 24..47 = |Zj-Zi|, 48 = 1, 49..63 = 0.
// B[h,k]: 0..23 = Zj*W1c+W1b, 24..47 = W1d, 48 = tj+b1 (built flat, then regs).
#define LSTR 72
#define TC 64
__global__ __launch_bounds__(256) void k_attn(
    const unsigned* __restrict__ Zjp, const unsigned* __restrict__ Zip,
    const float* __restrict__ W1, const float* __restrict__ b1,
    const float* __restrict__ W2,
    const float* __restrict__ mask, unsigned short* __restrict__ probs)
{
    int row = blockIdx.x;       // b*S + s
    int b = row >> 10;
    int tid = threadIdx.x;
    int lane = tid & 63, wv = tid >> 6;
    int quad = lane >> 4, col = lane & 15;

    __shared__ __align__(16) unsigned short sAB[2][TC*LSTR]; // B-build flat, then A dbuf
    __shared__ __align__(16) float sLog[SS];
    __shared__ unsigned sZjp[12];
    __shared__ float sW2[HIDD];
    __shared__ float sRed[4];
    unsigned short* sABf = &sAB[0][0];   // flat view (rows 0..127)

    if (tid < 12) sZjp[tid] = Zjp[(size_t)row*12 + tid];
    if (tid < HIDD) sW2[tid] = W2[tid];
    __syncthreads();

    // ---- build B flat (rows h = 0..95, k = 0..63) ----
    if (tid < HIDD) {
        int h = tid;
        float zj[24];
        #pragma unroll
        for (int u = 0; u < 12; ++u) {
            unsigned z = sZjp[u];
            zj[2*u]   = __uint_as_float(z << 16);
            zj[2*u+1] = __uint_as_float(z & 0xffff0000u);
        }
        float tj = b1[h];
        #pragma unroll
        for (int d = 0; d < DD; ++d) tj = fmaf(zj[d], W1[d*HIDD + h], tj);
        unsigned short* rowp = sABf + h*LSTR;
        #pragma unroll
        for (int d = 0; d < DD; ++d)
            rowp[d] = f2bf(fmaf(zj[d], W1[(48+d)*HIDD + h], W1[(24+d)*HIDD + h]));
        #pragma unroll
        for (int d = 0; d < DD; ++d)
            rowp[24+d] = f2bf(W1[(72+d)*HIDD + h]);
        rowp[48] = f2bf(tj);
        #pragma unroll
        for (int k = 49; k < 64; ++k) rowp[k] = 0;
    }
    __syncthreads();

    // hoist B fragments (h-side, MFMA A-operand) + per-lane w2 coeffs
    short8 bfr[6][2];
    #pragma unroll
    for (int nf = 0; nf < 6; ++nf)
        #pragma unroll
        for (int kt = 0; kt < 2; ++kt)
            bfr[nf][kt] = *(const short8*)&sABf[(nf*16 + col)*LSTR + kt*32 + quad*8];
    float4 w2q[6];
    #pragma unroll
    for (int nf = 0; nf < 6; ++nf)
        w2q[nf] = *(const float4*)&sW2[nf*16 + quad*4];
    __syncthreads();   // sAB now reused as A double-buffer

    // constant region k=48..63, both buffers (written once)
    if (tid < 128) {
        int bf = tid >> 6, r = tid & 63;
        unsigned short* rowp = &sAB[bf][r*LSTR];
        uint4 w0; w0.x = 0x3F80u; w0.y = 0; w0.z = 0; w0.w = 0;
        *(uint4*)&rowp[48] = w0;
        uint4 zz; zz.x = 0; zz.y = 0; zz.z = 0; zz.w = 0;
        *(uint4*)&rowp[56] = zz;
    }

    int t_loc = tid >> 2, ss = tid & 3;
    const unsigned* zbase = Zip + (size_t)(b << 10) * 12;

    // A-pack for one chunk (4 threads per t-row; each does 3 q-uints)
    auto pack = [&](int chunk, int bf) {
        int t = chunk*TC + t_loc;
        const unsigned* zr = zbase + (size_t)t*12;
        unsigned short* rowp = &sAB[bf][t_loc*LSTR];
        if (ss < 3) {
            uint4 cp = *(const uint4*)(zr + 4*ss);
            *(uint4*)&rowp[8*ss] = cp;
        }
        unsigned myz[3];
        #pragma unroll
        for (int u = 0; u < 3; ++u) myz[u] = zr[3*ss + u];
        #pragma unroll
        for (int u = 0; u < 3; ++u) {
            unsigned za = sZjp[3*ss + u], zb = myz[u];
            float alo = __uint_as_float(za << 16);
            float ahi = __uint_as_float(za & 0xffff0000u);
            float blo = __uint_as_float(zb << 16);
            float bhi = __uint_as_float(zb & 0xffff0000u);
            unsigned dlo = __float_as_uint(fabsf(alo - blo)) + 0x8000u;
            unsigned dhi = __float_as_uint(fabsf(ahi - bhi)) + 0x8000u;
            *(unsigned*)&rowp[24 + 6*ss + 2*u] =
                __builtin_amdgcn_perm(dhi, dlo, 0x07060302u);
        }
    };

    pack(0, 0);
    __syncthreads();

    for (int chunk = 0; chunk < SS/TC; ++chunk) {
        int cur = chunk & 1;
        if (chunk + 1 < SS/TC) pack(chunk + 1, cur ^ 1);

        // MFMA: D[h][t]; per-lane fold over (hf, reg), cross-quad reduce
        int arow = wv*16 + col;
        short8 av0 = *(const short8*)&sAB[cur][arow*LSTR + quad*8];
        short8 av1 = *(const short8*)&sAB[cur][arow*LSTR + 32 + quad*8];
        float s0 = 0.f;
        #pragma unroll
        for (int hf = 0; hf < 6; ++hf) {
            floatx4 a0 = {0.f,0.f,0.f,0.f};
            a0 = __builtin_amdgcn_mfma_f32_16x16x32_bf16(bfr[hf][0], av0, a0, 0, 0, 0);
            a0 = __builtin_amdgcn_mfma_f32_16x16x32_bf16(bfr[hf][1], av1, a0, 0, 0, 0);
            float w2v[4] = {w2q[hf].x, w2q[hf].y, w2q[hf].z, w2q[hf].w};
            #pragma unroll
            for (int r = 0; r < 4; ++r)
                s0 = fmaf(fmaxf(a0[r], 0.f), w2v[r], s0);
        }
        s0 += __shfl_xor(s0, 16, 64);
        s0 += __shfl_xor(s0, 32, 64);
        if (lane < 16)
            sLog[chunk*TC + wv*16 + lane] = s0;
        __syncthreads();
    }

    // ---- softmax ----
    float lv[4];
    #pragma unroll
    for (int i = 0; i < 4; ++i) {
        int t = tid + i*256;
        lv[i] = sLog[t] + (1.0f - mask[(size_t)(b<<10) + t]) * (-3.402823466e+38f);
    }
    float m = fmaxf(fmaxf(lv[0], lv[1]), fmaxf(lv[2], lv[3]));
    #pragma unroll
    for (int off = 32; off; off >>= 1) m = fmaxf(m, __shfl_down(m, off, 64));
    if (lane == 0) sRed[wv] = m;
    __syncthreads();
    float M = fmaxf(fmaxf(sRed[0], sRed[1]), fmaxf(sRed[2], sRed[3]));
    float e[4]; float ssum = 0.f;
    #pragma unroll
    for (int i = 0; i < 4; ++i) { e[i] = expf(lv[i] - M); ssum += e[i]; }
    #pragma unroll
    for (int off = 32; off; off >>= 1) ssum += __shfl_down(ssum, off, 64);
    __syncthreads();
    if (lane == 0) sRed[wv] = ssum;
    __syncthreads();
    float inv = 1.0f / (sRed[0] + sRed[1] + sRed[2] + sRed[3]);
    #pragma unroll
    for (int i = 0; i < 4; ++i)
        probs[(size_t)row*SS + tid + i*256] = f2bf(e[i] * inv);
}

// ---------------- Kernel 3: split-K=2 partial GEMM, 64x64 tile, gl16 -------
// (used for MLP1 only, K=2304). P[z][2048][768] f32.
__global__ __launch_bounds__(256) void k_mgemm_p(
    const unsigned short* __restrict__ A,
    const unsigned short* __restrict__ BT,
    float* __restrict__ P,
    int K, int bt_bstride)
{
    __shared__ __align__(16) unsigned short sA[64*64];
    __shared__ __align__(16) unsigned short sB[64*64];
    int tid = threadIdx.x;
    int w = tid >> 6, lane = tid & 63;
    int quad = lane >> 4, col = lane & 15;

    int n0 = blockIdx.x * 64, m0 = blockIdx.y * 64;
    int z = blockIdx.z;
    int kslice = K >> 1;
    int k0 = z * kslice;
    int nk = kslice >> 6;
    const unsigned short* Bb = BT + (size_t)(m0 >> 10) * bt_bstride;

    int srow = lane >> 3;
    int skc  = (lane & 7) * 8;

    floatx4 acc[4];
    #pragma unroll
    for (int nf = 0; nf < 4; ++nf) acc[nf] = (floatx4){0.f,0.f,0.f,0.f};

    for (int kb = 0; kb < nk; ++kb) {
        int kofs = k0 + kb*64;
        #pragma unroll
        for (int i = 0; i < 2; ++i) {
            int rbase = w*16 + i*8;
            gl16(A  + (size_t)(m0 + rbase + srow)*K + kofs + skc, &sA[rbase*64]);
            gl16(Bb + (size_t)(n0 + rbase + srow)*K + kofs + skc, &sB[rbase*64]);
        }
        __syncthreads();
        #pragma unroll
        for (int kt = 0; kt < 2; ++kt) {
            short8 av = *(const short8*)&sA[(w*16 + col)*64 + kt*32 + quad*8];
            #pragma unroll
            for (int nf = 0; nf < 4; ++nf) {
                short8 bv = *(const short8*)&sB[(nf*16 + col)*64 + kt*32 + quad*8];
                acc[nf] = __builtin_amdgcn_mfma_f32_16x16x32_bf16(av, bv, acc[nf], 0, 0, 0);
            }
        }
        __syncthreads();
    }

    float* Pz = P + (size_t)z*NRR*768;
    #pragma unroll
    for (int nf = 0; nf < 4; ++nf) {
        int n = n0 + nf*16 + col;
        #pragma unroll
        for (int r = 0; r < 4; ++r) {
            int m = w*16 + quad*4 + r;
            Pz[(size_t)(m0 + m)*768 + n] = acc[nf][r];
        }
    }
}

// ---------------- Kernel 3b: no-split GEMM, 64Mx32N, fused epilogue --------
// MODE 0: msgin builder (ctx | hj | ctx*hj, bf16)
// MODE 2: out = f32(alpha*(acc + bias))
template<int MODE>
__global__ __launch_bounds__(256) void k_mgemm_nf(
    const unsigned short* __restrict__ A,
    const unsigned short* __restrict__ BT,
    const float* __restrict__ bias,
    const float* __restrict__ Hj,
    const float* __restrict__ alpha_p,
    void* __restrict__ Cout,
    int K, int bt_bstride)
{
    __shared__ __align__(16) unsigned short sA[64*64];
    __shared__ __align__(16) unsigned short sB[32*64];
    int tid = threadIdx.x;
    int w = tid >> 6, lane = tid & 63;
    int quad = lane >> 4, col = lane & 15;

    int n0 = blockIdx.x * 32, m0 = blockIdx.y * 64;
    int nk = K >> 6;
    const unsigned short* Bb = BT + (size_t)(m0 >> 10) * bt_bstride;

    int srow = lane >> 3;
    int skc  = (lane & 7) * 8;

    floatx4 acc[2];
    acc[0] = (floatx4){0.f,0.f,0.f,0.f};
    acc[1] = (floatx4){0.f,0.f,0.f,0.f};

    for (int kb = 0; kb < nk; ++kb) {
        int kofs = kb*64;
        gl16(A  + (size_t)(m0 + w*16     + srow)*K + kofs + skc, &sA[(w*16)*64]);
        gl16(A  + (size_t)(m0 + w*16 + 8 + srow)*K + kofs + skc, &sA[(w*16 + 8)*64]);
        gl16(Bb + (size_t)(n0 + w*8      + srow)*K + kofs + skc, &sB[(w*8)*64]);
        __syncthreads();
        #pragma unroll
        for (int kt = 0; kt < 2; ++kt) {
            short8 av = *(const short8*)&sA[(w*16 + col)*64 + kt*32 + quad*8];
            #pragma unroll
            for (int nf = 0; nf < 2; ++nf) {
                short8 bv = *(const short8*)&sB[(nf*16 + col)*64 + kt*32 + quad*8];
                acc[nf] = __builtin_amdgcn_mfma_f32_16x16x32_bf16(av, bv, acc[nf], 0, 0, 0);
            }
        }
        __syncthreads();
    }

    float alpha = (MODE == 2) ? alpha_p[0] : 1.0f;
    #pragma unroll
    for (int nf = 0; nf < 2; ++nf) {
        int n = n0 + nf*16 + col;
        #pragma unroll
        for (int r = 0; r < 4; ++r) {
            int m = w*16 + quad*4 + r;
            size_t g = (size_t)(m0 + m);
            float v = acc[nf][r];
            if (MODE == 0) {
                float hj = Hj[g*HH + n];
                unsigned short* msgin = (unsigned short*)Cout;
                msgin[g*VINN + n]        = f2bf(v);
                msgin[g*VINN + HH + n]   = f2bf(hj);
                msgin[g*VINN + 2*HH + n] = f2bf(v*hj);
            } else {
                ((float*)Cout)[g*HH + n] = alpha*(v + bias[n]);
            }
        }
    }
}

// ---------------- Kernel 4: reduce-epilogue (2 partials) — MLP1 only -------
__global__ __launch_bounds__(256) void k_epi1(
    const float* __restrict__ P,
    const float* __restrict__ bias,
    unsigned short* __restrict__ Y1)
{
    int idx = blockIdx.x*256 + threadIdx.x;     // 0 .. 2048*192-1
    int g = idx / 192, c = (idx % 192) * 4;
    float4 v0 = *(const float4*)(P + (size_t)g*768 + c);
    float4 v1 = *(const float4*)(P + (size_t)NRR*768 + (size_t)g*768 + c);
    float4 b4 = *(const float4*)(bias + c);
    uint2 wy;
    wy.x = pack2(fmaxf(v0.x+v1.x+b4.x, 0.f), fmaxf(v0.y+v1.y+b4.y, 0.f));
    wy.y = pack2(fmaxf(v0.z+v1.z+b4.z, 0.f), fmaxf(v0.w+v1.w+b4.w, 0.f));
    *(uint2*)&Y1[(size_t)g*VHIDD + c] = wy;
}

extern "C" void kernel_launch(void* const* d_in, const int* in_sizes, int n_in,
                              void* d_out, int out_size, void* d_ws, size_t ws_size,
                              hipStream_t stream)
{
    const float* Hj   = (const float*)d_in[0];
    const float* Hi   = (const float*)d_in[1];
    const float* mask = (const float*)d_in[2];
    const float* Wpj  = (const float*)d_in[3];
    const float* Wpi  = (const float*)d_in[4];
    const float* W1   = (const float*)d_in[5];
    const float* b1   = (const float*)d_in[6];
    const float* W2   = (const float*)d_in[7];
    const float* Wv1  = (const float*)d_in[9];
    const float* bv1  = (const float*)d_in[10];
    const float* Wv2  = (const float*)d_in[11];
    const float* bv2  = (const float*)d_in[12];
    const float* alpha = (const float*)d_in[13];
    float* out = (float*)d_out;

    const int NR = NRR;                   // 2048
    char* p = (char*)d_ws;
    auto alloc = [&](size_t bytes) {
        char* r = p; p += (bytes + 255) & ~(size_t)255; return r;
    };
    unsigned* Zjp          = (unsigned*)alloc((size_t)NR*12*4);
    unsigned* Zip          = (unsigned*)alloc((size_t)NR*12*4);
    unsigned short* probsb = (unsigned short*)alloc((size_t)NR*SS*2);
    unsigned short* HiT    = (unsigned short*)alloc((size_t)BB*HH*SS*2);
    unsigned short* Wv1T   = (unsigned short*)alloc((size_t)VHIDD*VINN*2);
    unsigned short* Wv2T   = (unsigned short*)alloc((size_t)HH*VHIDD*2);
    unsigned short* msginb = (unsigned short*)alloc((size_t)NR*VINN*2);
    unsigned short* Y1b    = (unsigned short*)alloc((size_t)NR*VHIDD*2);
    float* Part            = (float*)alloc((size_t)2*NR*768*4);

    // prep: 64 zproj blocks + 1728 (Wv1T) + 576 (Wv2T) + 1536 (HiT) tconv blocks
    k_prep<<<64 + 1728 + 576 + 1536, 256, 0, stream>>>(
        Hj, Hi, Wpj, Wpi, Wv1, Wv2, Zjp, Zip, Wv1T, Wv2T, HiT);

    k_attn<<<NR, 256, 0, stream>>>(Zjp, Zip, W1, b1, W2, mask, probsb);

    // ctx GEMM: M=2048 (batch via bt stride), N=768, K=1024, no split,
    // fused msgin epilogue. 24 x 32 = 768 blocks.
    k_mgemm_nf<0><<<dim3(HH/32, NR/64), 256, 0, stream>>>(
        probsb, HiT, nullptr, Hj, alpha, msginb, SS, HH*SS);

    // MLP GEMM1: K=2304, split 2 + reduce-epilogue
    k_mgemm_p<<<dim3(VHIDD/64, NR/64, 2), 256, 0, stream>>>(
        msginb, Wv1T, Part, VINN, 0);
    k_epi1<<<NR*192/256, 256, 0, stream>>>(Part, bv1, Y1b);

    // MLP GEMM2: K=768, no split, fused f32 epilogue. 768 blocks.
    k_mgemm_nf<2><<<dim3(HH/32, NR/64), 256, 0, stream>>>(
        Y1b, Wv2T, bv2, nullptr, alpha, out, VHIDD, 0);
}

// Round 13
// 196.836 us; speedup vs baseline: 2.9160x; 1.0255x over previous
//
#include <hip/hip_runtime.h>
#include <math.h>

#define BB   2
#define SS   1024
#define HH   768
#define DD   24
#define HIDD 96
#define VINN 2304   // 3*H
#define VHIDD 768
#define NRR  2048   // BB*SS

typedef __attribute__((ext_vector_type(8))) short short8;
typedef __attribute__((ext_vector_type(4))) float floatx4;

static __device__ inline unsigned short f2bf(float x) {
    unsigned int u = __float_as_uint(x);
    u = (u + 0x7FFFu + ((u >> 16) & 1u)) >> 16;
    return (unsigned short)u;
}
static __device__ inline unsigned int pack2(float a, float b) {
    return (unsigned int)f2bf(a) | ((unsigned int)f2bf(b) << 16);
}

// async global -> LDS, 16 B per lane; LDS dest = wave-uniform base + lane*16
static __device__ inline void gl16(const unsigned short* g, unsigned short* l) {
    __builtin_amdgcn_global_load_lds(
        (const __attribute__((address_space(1))) unsigned int*)g,
        (__attribute__((address_space(3))) unsigned int*)l,
        16, 0, 0);
}

// ---------------- Kernel 0: fused prep --------------------------------------
// blocks 0..63: Z projections (MFMA), packed-bf16 output.
// blocks 64..: f32->bf16 transpose-convert for Wv1T / Wv2T / HiT.
__global__ __launch_bounds__(256) void k_prep(
    const float* __restrict__ Hj, const float* __restrict__ Hi,
    const float* __restrict__ Wpj, const float* __restrict__ Wpi,
    const float* __restrict__ Wv1, const float* __restrict__ Wv2,
    unsigned* __restrict__ Zjp, unsigned* __restrict__ Zip,
    unsigned short* __restrict__ Wv1T, unsigned short* __restrict__ Wv2T,
    unsigned short* __restrict__ HiT)
{
    __shared__ __align__(16) unsigned short sAz[64][72];
    __shared__ __align__(16) unsigned short sBTz[32][72];
    __shared__ float tile[32][33];
    int bid = blockIdx.x;
    int tid = threadIdx.x;

    if (bid < 64) {
        // ---------------- zproj ----------------
        int w = tid >> 6, lane = tid & 63;
        int quad = lane >> 4, col = lane & 15;
        int m0 = bid * 64;
        bool isJ = (m0 < NRR);
        const float* src = isJ ? Hj : Hi;
        const float* Wp  = isJ ? Wpj : Wpi;
        unsigned* Zp     = isJ ? Zjp : Zip;
        int rowbase = isJ ? m0 : (m0 - NRR);

        floatx4 acc[2];
        acc[0] = (floatx4){0.f,0.f,0.f,0.f};
        acc[1] = (floatx4){0.f,0.f,0.f,0.f};

        for (int kb = 0; kb < HH; kb += 64) {
            #pragma unroll
            for (int i = 0; i < 4; ++i) {
                int f4 = tid + i*256;
                int r = f4 >> 4, c4 = f4 & 15;
                float4 v = *(const float4*)(src + (size_t)(rowbase + r)*HH + kb + c4*4);
                uint2 pkt; pkt.x = pack2(v.x, v.y); pkt.y = pack2(v.z, v.w);
                *(uint2*)&sAz[r][c4*4] = pkt;
            }
            {
                const float* wsrc = Wp + (size_t)kb*DD;
                #pragma unroll
                for (int i = 0; i < 6; ++i) {
                    int idx = tid + i*256;
                    int k = idx / DD, n = idx % DD;
                    sBTz[n][k] = f2bf(wsrc[idx]);
                }
            }
            __syncthreads();
            #pragma unroll
            for (int kt = 0; kt < 2; ++kt) {
                short8 av = *(const short8*)&sAz[w*16 + col][kt*32 + quad*8];
                #pragma unroll
                for (int nt = 0; nt < 2; ++nt) {
                    short8 bv = *(const short8*)&sBTz[nt*16 + col][kt*32 + quad*8];
                    acc[nt] = __builtin_amdgcn_mfma_f32_16x16x32_bf16(av, bv, acc[nt], 0, 0, 0);
                }
            }
            __syncthreads();
        }
        #pragma unroll
        for (int nt = 0; nt < 2; ++nt) {
            #pragma unroll
            for (int r = 0; r < 4; ++r) {
                float v = acc[nt][r];
                float vn = __shfl_xor(v, 1, 64);
                int n = nt*16 + col;
                if (!(col & 1) && n < DD) {
                    int m = w*16 + quad*4 + r;
                    Zp[(size_t)(rowbase + m)*12 + (n >> 1)] = pack2(v, vn);
                }
            }
        }
        return;
    }

    // ---------------- tconv segments ----------------
    int b2 = bid - 64;
    const float* in; unsigned short* out; int R, C, r0, c0;
    if (b2 < 1728) {                 // Wv1T: [2304][768] -> [768][2304]
        in = Wv1; out = Wv1T; R = VINN; C = VHIDD;
        c0 = (b2 % 24) * 32; r0 = (b2 / 24) * 32;
    } else if (b2 < 2304) {          // Wv2T: [768][768] -> [768][768]
        int t = b2 - 1728;
        in = Wv2; out = Wv2T; R = VHIDD; C = HH;
        c0 = (t % 24) * 32; r0 = (t / 24) * 32;
    } else {                          // HiT: per batch [1024][768] -> [768][1024]
        int t = b2 - 2304;
        int z = t / 768; t %= 768;
        in = Hi + (size_t)z*SS*HH; out = HiT + (size_t)z*HH*SS;
        R = SS; C = HH;
        c0 = (t % 24) * 32; r0 = (t / 24) * 32;
    }
    int tc = tid & 31, tr = tid >> 5;
    #pragma unroll
    for (int i = 0; i < 4; ++i)
        tile[tr + i*8][tc] = in[(size_t)(r0 + tr + i*8)*C + c0 + tc];
    __syncthreads();
    #pragma unroll
    for (int i = 0; i < 4; ++i)
        out[(size_t)(c0 + tr + i*8)*R + r0 + tc] = f2bf(tile[tc][tr + i*8]);
}

// ---------------- Kernel 2: MFMA logits + softmax -> probs (bf16) ----------
// TC=64 chunks, double-buffered (23 KB LDS).
// A[t,k]: 0..23 = Zi, 24..47 = |Zj-Zi|, 48 = 1, 49..63 = 0.
// B[h,k]: 0..23 = Zj*W1c+W1b, 24..47 = W1d, 48 = tj+b1 (built flat, then regs).
#define LSTR 72
#define TC 64
__global__ __launch_bounds__(256) void k_attn(
    const unsigned* __restrict__ Zjp, const unsigned* __restrict__ Zip,
    const float* __restrict__ W1, const float* __restrict__ b1,
    const float* __restrict__ W2,
    const float* __restrict__ mask, unsigned short* __restrict__ probs)
{
    int row = blockIdx.x;       // b*S + s
    int b = row >> 10;
    int tid = threadIdx.x;
    int lane = tid & 63, wv = tid >> 6;
    int quad = lane >> 4, col = lane & 15;

    __shared__ __align__(16) unsigned short sAB[2][TC*LSTR]; // B-build flat, then A dbuf
    __shared__ __align__(16) float sLog[SS];
    __shared__ unsigned sZjp[12];
    __shared__ float sW2[HIDD];
    __shared__ float sRed[4];
    unsigned short* sABf = &sAB[0][0];   // flat view (rows 0..127)

    if (tid < 12) sZjp[tid] = Zjp[(size_t)row*12 + tid];
    if (tid < HIDD) sW2[tid] = W2[tid];
    __syncthreads();

    // ---- build B flat (rows h = 0..95, k = 0..63) ----
    if (tid < HIDD) {
        int h = tid;
        float zj[24];
        #pragma unroll
        for (int u = 0; u < 12; ++u) {
            unsigned z = sZjp[u];
            zj[2*u]   = __uint_as_float(z << 16);
            zj[2*u+1] = __uint_as_float(z & 0xffff0000u);
        }
        float tj = b1[h];
        #pragma unroll
        for (int d = 0; d < DD; ++d) tj = fmaf(zj[d], W1[d*HIDD + h], tj);
        unsigned short* rowp = sABf + h*LSTR;
        #pragma unroll
        for (int d = 0; d < DD; ++d)
            rowp[d] = f2bf(fmaf(zj[d], W1[(48+d)*HIDD + h], W1[(24+d)*HIDD + h]));
        #pragma unroll
        for (int d = 0; d < DD; ++d)
            rowp[24+d] = f2bf(W1[(72+d)*HIDD + h]);
        rowp[48] = f2bf(tj);
        #pragma unroll
        for (int k = 49; k < 64; ++k) rowp[k] = 0;
    }
    __syncthreads();

    // hoist B fragments (h-side, MFMA A-operand) + per-lane w2 coeffs
    short8 bfr[6][2];
    #pragma unroll
    for (int nf = 0; nf < 6; ++nf)
        #pragma unroll
        for (int kt = 0; kt < 2; ++kt)
            bfr[nf][kt] = *(const short8*)&sABf[(nf*16 + col)*LSTR + kt*32 + quad*8];
    float4 w2q[6];
    #pragma unroll
    for (int nf = 0; nf < 6; ++nf)
        w2q[nf] = *(const float4*)&sW2[nf*16 + quad*4];
    __syncthreads();   // sAB now reused as A double-buffer

    // constant region k=48..63, both buffers (written once)
    if (tid < 128) {
        int bf = tid >> 6, r = tid & 63;
        unsigned short* rowp = &sAB[bf][r*LSTR];
        uint4 w0; w0.x = 0x3F80u; w0.y = 0; w0.z = 0; w0.w = 0;
        *(uint4*)&rowp[48] = w0;
        uint4 zz; zz.x = 0; zz.y = 0; zz.z = 0; zz.w = 0;
        *(uint4*)&rowp[56] = zz;
    }

    int t_loc = tid >> 2, ss = tid & 3;
    const unsigned* zbase = Zip + (size_t)(b << 10) * 12;

    // hoist Zj unpack (chunk-invariant) for this thread's 3 q-uints
    float zalo[3], zahi[3];
    #pragma unroll
    for (int u = 0; u < 3; ++u) {
        unsigned za = sZjp[3*ss + u];
        zalo[u] = __uint_as_float(za << 16);
        zahi[u] = __uint_as_float(za & 0xffff0000u);
    }

    // A-pack for one chunk (4 threads per t-row; each does 3 q-uints)
    auto pack = [&](int chunk, int bf) {
        int t = chunk*TC + t_loc;
        const unsigned* zr = zbase + (size_t)t*12;
        unsigned short* rowp = &sAB[bf][t_loc*LSTR];
        if (ss < 3) {
            uint4 cp = *(const uint4*)(zr + 4*ss);
            *(uint4*)&rowp[8*ss] = cp;
        }
        unsigned myz[3];
        #pragma unroll
        for (int u = 0; u < 3; ++u) myz[u] = zr[3*ss + u];
        #pragma unroll
        for (int u = 0; u < 3; ++u) {
            unsigned zb = myz[u];
            float blo = __uint_as_float(zb << 16);
            float bhi = __uint_as_float(zb & 0xffff0000u);
            unsigned dlo = __float_as_uint(fabsf(zalo[u] - blo)) + 0x8000u;
            unsigned dhi = __float_as_uint(fabsf(zahi[u] - bhi)) + 0x8000u;
            *(unsigned*)&rowp[24 + 6*ss + 2*u] =
                __builtin_amdgcn_perm(dhi, dlo, 0x07060302u);
        }
    };

    pack(0, 0);
    __syncthreads();

    for (int chunk = 0; chunk < SS/TC; ++chunk) {
        int cur = chunk & 1;
        if (chunk + 1 < SS/TC) pack(chunk + 1, cur ^ 1);

        // MFMA: D[h][t]; per-lane fold over (hf, reg), cross-quad reduce
        int arow = wv*16 + col;
        short8 av0 = *(const short8*)&sAB[cur][arow*LSTR + quad*8];
        short8 av1 = *(const short8*)&sAB[cur][arow*LSTR + 32 + quad*8];
        float s0 = 0.f;
        #pragma unroll
        for (int hf = 0; hf < 6; ++hf) {
            floatx4 a0 = {0.f,0.f,0.f,0.f};
            a0 = __builtin_amdgcn_mfma_f32_16x16x32_bf16(bfr[hf][0], av0, a0, 0, 0, 0);
            a0 = __builtin_amdgcn_mfma_f32_16x16x32_bf16(bfr[hf][1], av1, a0, 0, 0, 0);
            float w2v[4] = {w2q[hf].x, w2q[hf].y, w2q[hf].z, w2q[hf].w};
            #pragma unroll
            for (int r = 0; r < 4; ++r)
                s0 = fmaf(fmaxf(a0[r], 0.f), w2v[r], s0);
        }
        s0 += __shfl_xor(s0, 16, 64);
        s0 += __shfl_xor(s0, 32, 64);
        if (lane < 16)
            sLog[chunk*TC + wv*16 + lane] = s0;
        __syncthreads();
    }

    // ---- softmax ----
    float lv[4];
    #pragma unroll
    for (int i = 0; i < 4; ++i) {
        int t = tid + i*256;
        lv[i] = sLog[t] + (1.0f - mask[(size_t)(b<<10) + t]) * (-3.402823466e+38f);
    }
    float m = fmaxf(fmaxf(lv[0], lv[1]), fmaxf(lv[2], lv[3]));
    #pragma unroll
    for (int off = 32; off; off >>= 1) m = fmaxf(m, __shfl_down(m, off, 64));
    if (lane == 0) sRed[wv] = m;
    __syncthreads();
    float M = fmaxf(fmaxf(sRed[0], sRed[1]), fmaxf(sRed[2], sRed[3]));
    float e[4]; float ssum = 0.f;
    #pragma unroll
    for (int i = 0; i < 4; ++i) { e[i] = expf(lv[i] - M); ssum += e[i]; }
    #pragma unroll
    for (int off = 32; off; off >>= 1) ssum += __shfl_down(ssum, off, 64);
    __syncthreads();
    if (lane == 0) sRed[wv] = ssum;
    __syncthreads();
    float inv = 1.0f / (sRed[0] + sRed[1] + sRed[2] + sRed[3]);
    #pragma unroll
    for (int i = 0; i < 4; ++i)
        probs[(size_t)row*SS + tid + i*256] = f2bf(e[i] * inv);
}

// ---------------- Kernel 3: no-split GEMM, 64Mx32N, fused epilogue ---------
// MODE 0: msgin builder (ctx | hj | ctx*hj, bf16)
// MODE 1: Y1 = bf16(relu(acc + bias))
// MODE 2: out = f32(alpha*(acc + bias))
template<int MODE>
__global__ __launch_bounds__(256) void k_mgemm_nf(
    const unsigned short* __restrict__ A,
    const unsigned short* __restrict__ BT,
    const float* __restrict__ bias,
    const float* __restrict__ Hj,
    const float* __restrict__ alpha_p,
    void* __restrict__ Cout,
    int K, int bt_bstride)
{
    __shared__ __align__(16) unsigned short sA[64*64];
    __shared__ __align__(16) unsigned short sB[32*64];
    int tid = threadIdx.x;
    int w = tid >> 6, lane = tid & 63;
    int quad = lane >> 4, col = lane & 15;

    int n0 = blockIdx.x * 32, m0 = blockIdx.y * 64;
    int nk = K >> 6;
    const unsigned short* Bb = BT + (size_t)(m0 >> 10) * bt_bstride;

    int srow = lane >> 3;
    int skc  = (lane & 7) * 8;

    floatx4 acc[2];
    acc[0] = (floatx4){0.f,0.f,0.f,0.f};
    acc[1] = (floatx4){0.f,0.f,0.f,0.f};

    for (int kb = 0; kb < nk; ++kb) {
        int kofs = kb*64;
        gl16(A  + (size_t)(m0 + w*16     + srow)*K + kofs + skc, &sA[(w*16)*64]);
        gl16(A  + (size_t)(m0 + w*16 + 8 + srow)*K + kofs + skc, &sA[(w*16 + 8)*64]);
        gl16(Bb + (size_t)(n0 + w*8      + srow)*K + kofs + skc, &sB[(w*8)*64]);
        __syncthreads();
        #pragma unroll
        for (int kt = 0; kt < 2; ++kt) {
            short8 av = *(const short8*)&sA[(w*16 + col)*64 + kt*32 + quad*8];
            #pragma unroll
            for (int nf = 0; nf < 2; ++nf) {
                short8 bv = *(const short8*)&sB[(nf*16 + col)*64 + kt*32 + quad*8];
                acc[nf] = __builtin_amdgcn_mfma_f32_16x16x32_bf16(av, bv, acc[nf], 0, 0, 0);
            }
        }
        __syncthreads();
    }

    float alpha = (MODE == 2) ? alpha_p[0] : 1.0f;
    #pragma unroll
    for (int nf = 0; nf < 2; ++nf) {
        int n = n0 + nf*16 + col;
        #pragma unroll
        for (int r = 0; r < 4; ++r) {
            int m = w*16 + quad*4 + r;
            size_t g = (size_t)(m0 + m);
            float v = acc[nf][r];
            if (MODE == 0) {
                float hj = Hj[g*HH + n];
                unsigned short* msgin = (unsigned short*)Cout;
                msgin[g*VINN + n]        = f2bf(v);
                msgin[g*VINN + HH + n]   = f2bf(hj);
                msgin[g*VINN + 2*HH + n] = f2bf(v*hj);
            } else if (MODE == 1) {
                ((unsigned short*)Cout)[g*VHIDD + n] =
                    f2bf(fmaxf(v + bias[n], 0.f));
            } else {
                ((float*)Cout)[g*HH + n] = alpha*(v + bias[n]);
            }
        }
    }
}

extern "C" void kernel_launch(void* const* d_in, const int* in_sizes, int n_in,
                              void* d_out, int out_size, void* d_ws, size_t ws_size,
                              hipStream_t stream)
{
    const float* Hj   = (const float*)d_in[0];
    const float* Hi   = (const float*)d_in[1];
    const float* mask = (const float*)d_in[2];
    const float* Wpj  = (const float*)d_in[3];
    const float* Wpi  = (const float*)d_in[4];
    const float* W1   = (const float*)d_in[5];
    const float* b1   = (const float*)d_in[6];
    const float* W2   = (const float*)d_in[7];
    const float* Wv1  = (const float*)d_in[9];
    const float* bv1  = (const float*)d_in[10];
    const float* Wv2  = (const float*)d_in[11];
    const float* bv2  = (const float*)d_in[12];
    const float* alpha = (const float*)d_in[13];
    float* out = (float*)d_out;

    const int NR = NRR;                   // 2048
    char* p = (char*)d_ws;
    auto alloc = [&](size_t bytes) {
        char* r = p; p += (bytes + 255) & ~(size_t)255; return r;
    };
    unsigned* Zjp          = (unsigned*)alloc((size_t)NR*12*4);
    unsigned* Zip          = (unsigned*)alloc((size_t)NR*12*4);
    unsigned short* probsb = (unsigned short*)alloc((size_t)NR*SS*2);
    unsigned short* HiT    = (unsigned short*)alloc((size_t)BB*HH*SS*2);
    unsigned short* Wv1T   = (unsigned short*)alloc((size_t)VHIDD*VINN*2);
    unsigned short* Wv2T   = (unsigned short*)alloc((size_t)HH*VHIDD*2);
    unsigned short* msginb = (unsigned short*)alloc((size_t)NR*VINN*2);
    unsigned short* Y1b    = (unsigned short*)alloc((size_t)NR*VHIDD*2);

    // prep: 64 zproj blocks + 1728 (Wv1T) + 576 (Wv2T) + 1536 (HiT) tconv blocks
    k_prep<<<64 + 1728 + 576 + 1536, 256, 0, stream>>>(
        Hj, Hi, Wpj, Wpi, Wv1, Wv2, Zjp, Zip, Wv1T, Wv2T, HiT);

    k_attn<<<NR, 256, 0, stream>>>(Zjp, Zip, W1, b1, W2, mask, probsb);

    // ctx GEMM: M=2048 (batch via bt stride), N=768, K=1024, no split,
    // fused msgin epilogue. 24 x 32 = 768 blocks.
    k_mgemm_nf<0><<<dim3(HH/32, NR/64), 256, 0, stream>>>(
        probsb, HiT, nullptr, Hj, alpha, msginb, SS, HH*SS);

    // MLP GEMM1: K=2304, no split, fused bias+relu epilogue. 768 blocks.
    k_mgemm_nf<1><<<dim3(VHIDD/32, NR/64), 256, 0, stream>>>(
        msginb, Wv1T, bv1, nullptr, alpha, Y1b, VINN, 0);

    // MLP GEMM2: K=768, no split, fused f32 epilogue. 768 blocks.
    k_mgemm_nf<2><<<dim3(HH/32, NR/64), 256, 0, stream>>>(
        Y1b, Wv2T, bv2, nullptr, alpha, out, VHIDD, 0);
}